// Round 6
// baseline (880.798 us; speedup 1.0000x reference)
//
#include <hip/hip_runtime.h>
#include <math.h>

// Problem constants (fixed by reference: b=4, n=2048, d=1024, H=16, DH=64)
#define BB    4
#define NN    2048
#define DD    1024
#define HH    16
#define DHD   64
#define INNER 1024
// log2(10000)/16 for inv_freq = 2^(-f * LOG2_10K_D16)
#define LOG2_10K_D16 0.8304820237218406f
// SCALE * log2(e): folded into Q at projection time -> attn uses raw exp2
#define SCALE_LOG2E 0.1803368801111601f

typedef short bf16x8 __attribute__((ext_vector_type(8)));   // 8 bf16 = 4 VGPRs
typedef short bf16x4 __attribute__((ext_vector_type(4)));   // 4 bf16 = 2 VGPRs
typedef float f32x4  __attribute__((ext_vector_type(4)));
typedef unsigned short u16x8 __attribute__((ext_vector_type(8)));

// async 16B/lane global->LDS (lane i lands at wave-uniform base + i*16)
#define ASYNC16(g, l) __builtin_amdgcn_global_load_lds( \
    (const __attribute__((address_space(1))) void*)(g),  \
    (__attribute__((address_space(3))) void*)(l), 16, 0, 0)

#define MFMA16(a, b, c) __builtin_amdgcn_mfma_f32_16x16x32_bf16((a), (b), (c), 0, 0, 0)

// ---------- fast exp2: raw v_exp_f32, no libm range guard ----------
static __device__ __forceinline__ float fexp2(float x) {
#if __has_builtin(__builtin_amdgcn_exp2f)
    return __builtin_amdgcn_exp2f(x);
#else
    float r;
    asm("v_exp_f32 %0, %1" : "=v"(r) : "v"(x));
    return r;
#endif
}

// ---------- bf16 helpers (manual RNE; no hip_bf16.h dependency) ----------
static __device__ __forceinline__ unsigned short f2bf(float f) {
    union { float f; unsigned int u; } v; v.f = f;
    unsigned int u = v.u;
    u += 0x7fffu + ((u >> 16) & 1u);
    return (unsigned short)(u >> 16);
}
// pack two f32 -> bf16x2 dword, round-half-up via +0x8000 then byte-perm.
static __device__ __forceinline__ unsigned int packbf2(float lo, float hi) {
    union { float f; unsigned int u; } a, b;
    a.f = lo; b.f = hi;
    return __builtin_amdgcn_perm(b.u + 0x8000u, a.u + 0x8000u, 0x07060302u);
}

// =====================================================================
// Pre-pass A: cast X fp32 -> bf16
// =====================================================================
__global__ __launch_bounds__(256) void cast_x_kernel(
    const float* __restrict__ X, unsigned short* __restrict__ Xb)
{
    const size_t i = ((size_t)blockIdx.x * 256 + threadIdx.x) * 8;
    const float4 a = *(const float4*)(X + i);
    const float4 b = *(const float4*)(X + i + 4);
    u16x8 o;
    o[0] = f2bf(a.x); o[1] = f2bf(a.y); o[2] = f2bf(a.z); o[3] = f2bf(a.w);
    o[4] = f2bf(b.x); o[5] = f2bf(b.y); o[6] = f2bf(b.z); o[7] = f2bf(b.w);
    *(u16x8*)(Xb + i) = o;
}

// =====================================================================
// Pre-pass B: transpose-cast W [K][N] fp32 -> Wt [N][K] bf16
// =====================================================================
__global__ __launch_bounds__(256) void tcast_kernel(
    const float* __restrict__ src, unsigned short* __restrict__ dst,
    int K, int N)
{
    __shared__ float ts[32][33];
    const int t = threadIdx.x;
    const int n0 = blockIdx.x * 32, k0 = blockIdx.y * 32;
    const int r = t >> 5, c = t & 31;
    #pragma unroll
    for (int p = 0; p < 4; ++p)
        ts[r + p * 8][c] = src[(size_t)(k0 + r + p * 8) * N + n0 + c];
    __syncthreads();
    #pragma unroll
    for (int p = 0; p < 4; ++p)
        dst[(size_t)(n0 + r + p * 8) * K + k0 + c] = f2bf(ts[c][r + p * 8]);
}

// =====================================================================
// Kernel 1: QKV projection via bf16 MFMA + fused RoPE + head-split.
// =====================================================================
__global__ __launch_bounds__(256) void proj_qkv_mfma(
    const unsigned short* __restrict__ Xb, const unsigned short* __restrict__ Wt,
    unsigned short* __restrict__ qb, unsigned short* __restrict__ kb,
    unsigned short* __restrict__ vb)
{
    __shared__ __align__(16) unsigned short As[128 * 32];
    __shared__ __align__(16) unsigned short Bs[128 * 32];

    const int t     = threadIdx.x;
    const int w     = t >> 6, lane = t & 63;
    const int lane4 = lane & 15, quad = lane >> 4, quad8 = quad * 8;
    const int wm    = w >> 1, wn = w & 1;
    const int m0    = blockIdx.y * 128, n0 = blockIdx.x * 128;

    const int srow = t >> 2, scol = (t & 3) * 8;
    const unsigned short* gA = Xb + (size_t)(m0 + srow) * DD + scol;
    const unsigned short* gB = Wt + (size_t)(n0 + srow) * DD + scol;
    unsigned short* lA = As + t * 8;
    unsigned short* lB = Bs + t * 8;

    f32x4 acc[4][4] = {};

    for (int k0 = 0; k0 < DD; k0 += 32) {
        __syncthreads();
        ASYNC16(gA + k0,            lA);
        ASYNC16(gA + 64 * DD + k0,  lA + 2048);
        ASYNC16(gB + k0,            lB);
        ASYNC16(gB + 64 * DD + k0,  lB + 2048);
        __syncthreads();

        bf16x8 a[4], b[4];
        #pragma unroll
        for (int i = 0; i < 4; ++i)
            a[i] = *(const bf16x8*)&As[(wm * 64 + i * 16 + lane4) * 32 + quad8];
        #pragma unroll
        for (int j = 0; j < 4; ++j)
            b[j] = *(const bf16x8*)&Bs[(wn * 64 + j * 16 + lane4) * 32 + quad8];
        #pragma unroll
        for (int i = 0; i < 4; ++i)
            #pragma unroll
            for (int j = 0; j < 4; ++j)
                acc[i][j] = MFMA16(a[i], b[j], acc[i][j]);
    }

    // ---- epilogue ----
    const int sec = n0 >> 10;                  // 0=q 1=k 2=v (uniform/block)

    if (sec == 2) {
        // V: transposed global layout, 4 consecutive n per lane -> uint2
        #pragma unroll
        for (int j = 0; j < 4; ++j) {
            const int csec = (n0 & 1023) + wn * 64 + j * 16;
            const int h    = csec >> 6;
            const int dh   = (csec & 63) + lane4;
            #pragma unroll
            for (int i = 0; i < 4; ++i) {
                const int rg0 = m0 + wm * 64 + i * 16 + quad * 4;
                const int b   = rg0 >> 11;
                const int n   = rg0 & 2047;
                uint2 pk;
                pk.x = packbf2(acc[i][j][0], acc[i][j][1]);
                pk.y = packbf2(acc[i][j][2], acc[i][j][3]);
                *(uint2*)(vb + (((size_t)b * HH + h) * DHD + dh) * NN + n) = pk;
            }
        }
    } else {
        unsigned short* dst = (sec == 0) ? qb : kb;
        const float qscale = (sec == 0) ? SCALE_LOG2E : 1.0f;
        #pragma unroll
        for (int j = 0; j < 4; ++j) {
            const int csec = (n0 & 1023) + wn * 64 + j * 16;
            const int h    = csec >> 6;
            const int dhb  = csec & 63;
            const int dh   = dhb + lane4;
            const bool rope = (dhb < 32);          // wave-uniform
            const float invf = fexp2(-(float)(dh >> 1) * LOG2_10K_D16);
            #pragma unroll
            for (int i = 0; i < 4; ++i) {
                #pragma unroll
                for (int r = 0; r < 4; ++r) {
                    const int rg = m0 + wm * 64 + i * 16 + quad * 4 + r;
                    const int b  = rg >> 11;
                    const int n  = rg & 2047;
                    float x = acc[i][j][r] * qscale;
                    if (rope) {
                        const float ang = (float)n * invf;
                        float s_, c_;
                        __sincosf(ang, &s_, &c_);
                        const float p = __shfl_xor(x, 1);
                        x = (lane4 & 1) ? fmaf(p, s_, x * c_)
                                        : fmaf(p, -s_, x * c_);
                    }
                    dst[(((size_t)b * HH + h) * NN + n) * DHD + dh] = f2bf(x);
                }
            }
        }
    }
}

// =====================================================================
// Kernel 2: flash attention, KEY-SPLIT waves, SINGLE-buffer wave-private
// staging, 32 KB LDS -> 5 blocks/CU (R6).
// R5 falsified phase-lock theory: barrier removal changed nothing ->
// the ~33% idle is the per-wave serial chain (ds_read -> QK MFMA ->
// exp2 -> pack -> PV MFMA) exposed at only 2 waves/SIMD. Fix = TLP:
// single-buffer is race-free under wave-private staging (per-wave DS
// ops execute in order: tile-kt reads are served before tile-kt+1
// writes to the same addresses), so ks/vs shrink to 32 KB and the
// epilogue overlay becomes a 32 KB two-phase reduction. 5 blocks/CU
// (launch_bounds (256,5)); 5 waves/SIMD hide each other's chain.
// XCD pinning kept: id%8 == bh%8 -> K/V L2-resident.
// =====================================================================
__global__ __launch_bounds__(256, 5) void attn_kernel(
    const unsigned short* __restrict__ qb, const unsigned short* __restrict__ kb,
    const unsigned short* __restrict__ vtb, unsigned short* __restrict__ aob)
{
    __shared__ __align__(16) unsigned char smem[32768];
    unsigned short (*ks)[64]  = (unsigned short (*)[64])smem;            // [128][64]  16KB
    unsigned short (*vs)[128] = (unsigned short (*)[128])(smem + 16384); // [64][128]  16KB

    const int t     = threadIdx.x;
    const int kq    = t >> 6;          // wave's key-quarter
    const int lane  = t & 63;
    const int lane4 = lane & 15;
    const int quad  = lane >> 4;
    const int quad8 = quad * 8;
    const int l7    = lane4 & 7;

    const int bid = blockIdx.x;
    const int bh  = bid & 63;          // id%8 = bh%8 -> per-XCD head groups
    const int q0  = (bid >> 6) * 64;
    const size_t hb = (size_t)bh * NN * DHD;

    // Q B-fragments for ALL 64 queries (held in registers whole kernel)
    bf16x8 qf[4][2];
    #pragma unroll
    for (int qt = 0; qt < 4; ++qt) {
        const unsigned short* qrow = qb + hb + (size_t)(q0 + qt * 16 + lane4) * DHD;
        qf[qt][0] = *(const bf16x8*)(qrow + quad8);
        qf[qt][1] = *(const bf16x8*)(qrow + 32 + quad8);
    }

    // ones A-fragment for the l-accumulating MFMA
    bf16x8 onesf;
    #pragma unroll
    for (int j = 0; j < 8; ++j) onesf[j] = (short)0x3F80;

    // ---- wave-private staging maps (each wave stages ONLY its keys) ----
    // K: 4 chunks, rows (within tile) = kq*16 + (lane>>3) + {0, 8, 64, 72},
    //    global col (lane&7)*8, LDS slot (lane&7)^(lane>>3) (row&7 == lane>>3)
    const int krow  = kq * 16 + (lane >> 3);
    const int kslot = ((lane & 7) ^ (lane >> 3)) * 8;
    const unsigned short* kg = kb + hb + (size_t)krow * DHD + (lane & 7) * 8;

    // V: 4 chunks s=0..3, rows = (lane>>2) + 16*s, key-group
    //    vm = 2kq + (lane&1) + ((lane>>1)&1)*8  (wave's 4 of 16 groups);
    //    8 keys -> logical slots (vm&7)*2 (lo4) and (vm&7)*2+1 (hi4),
    //    half-offset (vm>>3)*4, physical slot XOR row&7 (== vrow0&7).
    const int vrow0 = lane >> 2;
    const int vm    = 2 * kq + (lane & 1) + ((lane >> 1) & 1) * 8;
    const int vr7   = vrow0 & 7;
    const int halfo = (vm >> 3) * 4;
    const int colA  = ((((vm & 7) * 2)     ^ vr7) * 8) + halfo;
    const int colB  = ((((vm & 7) * 2 + 1) ^ vr7) * 8) + halfo;
    const unsigned short* vg = vtb + hb + (size_t)vrow0 * NN + vm * 8;

    f32x4 o[4][4], lacc[4];
    #pragma unroll
    for (int d = 0; d < 4; ++d)
        #pragma unroll
        for (int qt = 0; qt < 4; ++qt) o[d][qt] = (f32x4){0.f, 0.f, 0.f, 0.f};
    #pragma unroll
    for (int qt = 0; qt < 4; ++qt) lacc[qt] = (f32x4){0.f, 0.f, 0.f, 0.f};

    // ---- prologue: stage tile 0 (wave-private, no barrier) ----
    {
        const bf16x8 k0 = *(const bf16x8*)(kg);
        const bf16x8 k1 = *(const bf16x8*)(kg + 8 * DHD);
        const bf16x8 k2 = *(const bf16x8*)(kg + 64 * DHD);
        const bf16x8 k3 = *(const bf16x8*)(kg + 72 * DHD);
        const bf16x8 v0 = *(const bf16x8*)(vg);
        const bf16x8 v1 = *(const bf16x8*)(vg + (size_t)16 * NN);
        const bf16x8 v2 = *(const bf16x8*)(vg + (size_t)32 * NN);
        const bf16x8 v3 = *(const bf16x8*)(vg + (size_t)48 * NN);
        *(bf16x8*)&ks[krow][kslot]      = k0;
        *(bf16x8*)&ks[krow + 8][kslot]  = k1;
        *(bf16x8*)&ks[krow + 64][kslot] = k2;
        *(bf16x8*)&ks[krow + 72][kslot] = k3;
        #pragma unroll
        for (int s = 0; s < 4; ++s) {
            const bf16x8 vv = (s == 0) ? v0 : (s == 1) ? v1 : (s == 2) ? v2 : v3;
            bf16x4 lo = __builtin_shufflevector(vv, vv, 0, 1, 2, 3);
            bf16x4 hi = __builtin_shufflevector(vv, vv, 4, 5, 6, 7);
            *(bf16x4*)&vs[vrow0 + 16 * s][colA] = lo;
            *(bf16x4*)&vs[vrow0 + 16 * s][colB] = hi;
        }
    }

    for (int kt = 0; kt < NN / 128; ++kt) {
        const bool more = (kt + 1 < NN / 128);

        // ---- issue next tile's global loads (latency hides under compute) ----
        bf16x8 nk0, nk1, nk2, nk3, nv0, nv1, nv2, nv3;
        if (more) {
            const unsigned short* kgn = kg + (size_t)(kt + 1) * 128 * DHD;
            const unsigned short* vgn = vg + (kt + 1) * 128;
            nk0 = *(const bf16x8*)(kgn);
            nk1 = *(const bf16x8*)(kgn + 8 * DHD);
            nk2 = *(const bf16x8*)(kgn + 64 * DHD);
            nk3 = *(const bf16x8*)(kgn + 72 * DHD);
            nv0 = *(const bf16x8*)(vgn);
            nv1 = *(const bf16x8*)(vgn + (size_t)16 * NN);
            nv2 = *(const bf16x8*)(vgn + (size_t)32 * NN);
            nv3 = *(const bf16x8*)(vgn + (size_t)48 * NN);
        }

        // ---- QK A-fragments: this wave's 16 keys per 64-key subtile ----
        bf16x8 ak[2][2];
        #pragma unroll
        for (int sub = 0; sub < 2; ++sub) {
            const int row = sub * 64 + kq * 16 + lane4;
            ak[sub][0] = *(const bf16x8*)&ks[row][(quad ^ l7) * 8];
            ak[sub][1] = *(const bf16x8*)&ks[row][((quad + 4) ^ l7) * 8];
        }

        // ---- S^T -> exp2 -> P B-frags, all in registers ----
        bf16x8 pb[4];
        #pragma unroll
        for (int qt = 0; qt < 4; ++qt) {
            f32x4 z0 = (f32x4){0.f, 0.f, 0.f, 0.f};
            f32x4 z1 = (f32x4){0.f, 0.f, 0.f, 0.f};
            z0 = MFMA16(ak[0][0], qf[qt][0], z0);
            z0 = MFMA16(ak[0][1], qf[qt][1], z0);
            z1 = MFMA16(ak[1][0], qf[qt][0], z1);
            z1 = MFMA16(ak[1][1], qf[qt][1], z1);
            union { unsigned int u[4]; bf16x8 v; } pk;
            pk.u[0] = packbf2(fexp2(z0[0]), fexp2(z0[1]));
            pk.u[1] = packbf2(fexp2(z0[2]), fexp2(z0[3]));
            pk.u[2] = packbf2(fexp2(z1[0]), fexp2(z1[1]));
            pk.u[3] = packbf2(fexp2(z1[2]), fexp2(z1[3]));
            pb[qt] = pk.v;
            lacc[qt] = MFMA16(onesf, pb[qt], lacc[qt]);   // l partial (wave's keys)
        }

        // ---- O^T += V^T P^T over this wave's 32 keys ----
        #pragma unroll
        for (int d = 0; d < 4; ++d) {
            const bf16x8 av = *(const bf16x8*)&vs[d * 16 + lane4][((kq * 4 + quad) ^ l7) * 8];
            #pragma unroll
            for (int qt = 0; qt < 4; ++qt)
                o[d][qt] = MFMA16(av, pb[qt], o[d][qt]);
        }

        // ---- write-late: staged regs -> SAME buffer (in-order DS per wave
        //      guarantees this tile's reads were served first) ----
        if (more) {
            *(bf16x8*)&ks[krow][kslot]      = nk0;
            *(bf16x8*)&ks[krow + 8][kslot]  = nk1;
            *(bf16x8*)&ks[krow + 64][kslot] = nk2;
            *(bf16x8*)&ks[krow + 72][kslot] = nk3;
            #pragma unroll
            for (int s = 0; s < 4; ++s) {
                const bf16x8 vv = (s == 0) ? nv0 : (s == 1) ? nv1 : (s == 2) ? nv2 : nv3;
                bf16x4 lo = __builtin_shufflevector(vv, vv, 0, 1, 2, 3);
                bf16x4 hi = __builtin_shufflevector(vv, vv, 4, 5, 6, 7);
                *(bf16x4*)&vs[vrow0 + 16 * s][colA] = lo;
                *(bf16x4*)&vs[vrow0 + 16 * s][colB] = hi;
            }
        }
        // NO barrier in the main loop
    }

    // ---- epilogue: cross-wave O reduction, two-phase 32 KB overlay ----
    // pbuf[i][dh][col], i in {0,1}; col XOR-swizzled by writer quad
    // (derivable from dh: (dh>>2)&3 == quad) to avoid 4-way conflicts.
    __syncthreads();   // all waves done with ks/vs
    float* pbuf = (float*)smem;   // [2][64][64] f32 = 32 KB

    if (kq < 2) {
        // phase A: waves 0,1 write their partials to slab kq
        #pragma unroll
        for (int d = 0; d < 4; ++d)
            #pragma unroll
            for (int qt = 0; qt < 4; ++qt) {
                const int col = (qt * 16 + lane4) ^ (quad << 4);
                #pragma unroll
                for (int r = 0; r < 4; ++r) {
                    const int dh = d * 16 + quad * 4 + r;
                    pbuf[(kq * 64 + dh) * 64 + col] = o[d][qt][r];
                }
            }
    }
    __syncthreads();
    if (kq >= 2) {
        // phase B: waves 2,3 accumulate into slab kq-2
        #pragma unroll
        for (int d = 0; d < 4; ++d)
            #pragma unroll
            for (int qt = 0; qt < 4; ++qt) {
                const int col = (qt * 16 + lane4) ^ (quad << 4);
                #pragma unroll
                for (int r = 0; r < 4; ++r) {
                    const int dh = d * 16 + quad * 4 + r;
                    const int idx = ((kq - 2) * 64 + dh) * 64 + col;
                    pbuf[idx] += o[d][qt][r];
                }
            }
    }
    __syncthreads();

    // phase C: wave kq finalizes q-tile kq (all dh)
    f32x4 of[4];
    {
        const int qcol = (kq * 16 + lane4) ^ (quad << 4);
        #pragma unroll
        for (int d = 0; d < 4; ++d)
            #pragma unroll
            for (int r = 0; r < 4; ++r) {
                const int dh = d * 16 + quad * 4 + r;
                of[d][r] = pbuf[dh * 64 + qcol] + pbuf[(64 + dh) * 64 + qcol];
            }
    }
    __syncthreads();

    // l exchange (reuse first 1 KB of the overlay after O is consumed)
    if (quad == 0) {
        #pragma unroll
        for (int qt = 0; qt < 4; ++qt)
            pbuf[(kq * 4 + qt) * 16 + lane4] = lacc[qt][0];
    }
    __syncthreads();
    const float lt = pbuf[(0 * 4 + kq) * 16 + lane4] + pbuf[(1 * 4 + kq) * 16 + lane4]
                   + pbuf[(2 * 4 + kq) * 16 + lane4] + pbuf[(3 * 4 + kq) * 16 + lane4];
    const float linv = 1.0f / lt;

    const int b = bh >> 4, h = bh & 15;
    const int n = q0 + kq * 16 + lane4;
    unsigned short* obase = aob + ((size_t)b * NN + n) * INNER + h * DHD;
    #pragma unroll
    for (int d = 0; d < 4; ++d) {
        uint2 pk;
        pk.x = packbf2(of[d][0] * linv, of[d][1] * linv);
        pk.y = packbf2(of[d][2] * linv, of[d][3] * linv);
        *(uint2*)(obase + d * 16 + quad * 4) = pk;
    }
}

// =====================================================================
// Kernel 3: output projection via bf16 MFMA.
// =====================================================================
__global__ __launch_bounds__(256) void out_proj_mfma(
    const unsigned short* __restrict__ Ab, const unsigned short* __restrict__ Wt,
    const float* __restrict__ bias, float* __restrict__ C)
{
    __shared__ __align__(16) unsigned short As[128 * 32];
    __shared__ __align__(16) unsigned short Bs[128 * 32];

    const int t     = threadIdx.x;
    const int w     = t >> 6, lane = t & 63;
    const int lane4 = lane & 15, quad = lane >> 4, quad8 = quad * 8;
    const int wm    = w >> 1, wn = w & 1;
    const int m0    = blockIdx.y * 128, n0 = blockIdx.x * 128;

    const int srow = t >> 2, scol = (t & 3) * 8;
    const unsigned short* gA = Ab + (size_t)(m0 + srow) * INNER + scol;
    const unsigned short* gB = Wt + (size_t)(n0 + srow) * INNER + scol;
    unsigned short* lA = As + t * 8;
    unsigned short* lB = Bs + t * 8;

    f32x4 acc[4][4] = {};

    for (int k0 = 0; k0 < INNER; k0 += 32) {
        __syncthreads();
        ASYNC16(gA + k0,               lA);
        ASYNC16(gA + 64 * INNER + k0,  lA + 2048);
        ASYNC16(gB + k0,               lB);
        ASYNC16(gB + 64 * INNER + k0,  lB + 2048);
        __syncthreads();

        bf16x8 a[4], b[4];
        #pragma unroll
        for (int i = 0; i < 4; ++i)
            a[i] = *(const bf16x8*)&As[(wm * 64 + i * 16 + lane4) * 32 + quad8];
        #pragma unroll
        for (int j = 0; j < 4; ++j)
            b[j] = *(const bf16x8*)&Bs[(wn * 64 + j * 16 + lane4) * 32 + quad8];
        #pragma unroll
        for (int i = 0; i < 4; ++i)
            #pragma unroll
            for (int j = 0; j < 4; ++j)
                acc[i][j] = MFMA16(a[i], b[j], acc[i][j]);
    }

    #pragma unroll
    for (int j = 0; j < 4; ++j) {
        const int col = n0 + wn * 64 + j * 16 + lane4;
        const float bv = bias[col];
        #pragma unroll
        for (int i = 0; i < 4; ++i)
            #pragma unroll
            for (int r = 0; r < 4; ++r) {
                const int rg = m0 + wm * 64 + i * 16 + quad * 4 + r;
                C[(size_t)rg * DD + col] = acc[i][j][r] + bv;
            }
    }
}

// =====================================================================
extern "C" void kernel_launch(void* const* d_in, const int* in_sizes, int n_in,
                              void* d_out, int out_size, void* d_ws, size_t ws_size,
                              hipStream_t stream)
{
    const float* X    = (const float*)d_in[0];   // (4,2048,1024)
    const float* Wq   = (const float*)d_in[1];   // (1024,1024)
    const float* Wkv  = (const float*)d_in[2];   // (1024,2048)
    const float* Wout = (const float*)d_in[3];   // (1024,1024)
    const float* bout = (const float*)d_in[4];   // (1024,)
    float* out = (float*)d_out;

    // ws (bf16 elems): qb|kb|vtb|xb(=aob after proj)|WtAll|WoT = 75.5 MB
    const size_t E = (size_t)BB * HH * NN * DHD;   // 8388608
    unsigned short* qb  = (unsigned short*)d_ws;
    unsigned short* kb  = qb + E;
    unsigned short* vtb = kb + E;                // V^T [b][h][dh][n]
    unsigned short* xb  = vtb + E;               // X bf16; later reused as ao
    unsigned short* wt  = xb + E;                // [3072][1024] = WqT ; WkvT
    unsigned short* wo  = wt + (size_t)3072 * 1024;  // [1024][1024]

    cast_x_kernel<<<4096, 256, 0, stream>>>(X, xb);
    tcast_kernel<<<dim3(32, 32), 256, 0, stream>>>(Wq,   wt,               1024, 1024);
    tcast_kernel<<<dim3(64, 32), 256, 0, stream>>>(Wkv,  wt + 1024 * 1024, 1024, 2048);
    tcast_kernel<<<dim3(32, 32), 256, 0, stream>>>(Wout, wo,               1024, 1024);

    proj_qkv_mfma<<<dim3(3072 / 128, 8192 / 128), 256, 0, stream>>>(
        xb, wt, qb, kb, vtb);

    attn_kernel<<<dim3(NN / 64 * BB * HH), 256, 0, stream>>>(qb, kb, vtb, xb);

    out_proj_mfma<<<dim3(1024 / 128, 8192 / 128), 256, 0, stream>>>(
        xb, wo, bout, out);
}

// Round 7
// 692.648 us; speedup vs baseline: 1.2716x; 1.2716x over previous
//
#include <hip/hip_runtime.h>
#include <math.h>

// Problem constants (fixed by reference: b=4, n=2048, d=1024, H=16, DH=64)
#define BB    4
#define NN    2048
#define DD    1024
#define HH    16
#define DHD   64
#define INNER 1024
// log2(10000)/16 for inv_freq = 2^(-f * LOG2_10K_D16)
#define LOG2_10K_D16 0.8304820237218406f
// SCALE * log2(e): folded into Q at projection time -> attn uses raw exp2
#define SCALE_LOG2E 0.1803368801111601f

typedef short bf16x8 __attribute__((ext_vector_type(8)));   // 8 bf16 = 4 VGPRs
typedef short bf16x4 __attribute__((ext_vector_type(4)));   // 4 bf16 = 2 VGPRs
typedef float f32x4  __attribute__((ext_vector_type(4)));
typedef unsigned short u16x8 __attribute__((ext_vector_type(8)));

// async 16B/lane global->LDS (lane i lands at wave-uniform base + i*16)
#define ASYNC16(g, l) __builtin_amdgcn_global_load_lds( \
    (const __attribute__((address_space(1))) void*)(g),  \
    (__attribute__((address_space(3))) void*)(l), 16, 0, 0)

#define MFMA16(a, b, c) __builtin_amdgcn_mfma_f32_16x16x32_bf16((a), (b), (c), 0, 0, 0)

// ---------- fast exp2: raw v_exp_f32, no libm range guard ----------
static __device__ __forceinline__ float fexp2(float x) {
#if __has_builtin(__builtin_amdgcn_exp2f)
    return __builtin_amdgcn_exp2f(x);
#else
    float r;
    asm("v_exp_f32 %0, %1" : "=v"(r) : "v"(x));
    return r;
#endif
}

// ---------- bf16 helpers (manual RNE; no hip_bf16.h dependency) ----------
static __device__ __forceinline__ unsigned short f2bf(float f) {
    union { float f; unsigned int u; } v; v.f = f;
    unsigned int u = v.u;
    u += 0x7fffu + ((u >> 16) & 1u);
    return (unsigned short)(u >> 16);
}
// pack two f32 -> bf16x2 dword, round-half-up via +0x8000 then byte-perm.
static __device__ __forceinline__ unsigned int packbf2(float lo, float hi) {
    union { float f; unsigned int u; } a, b;
    a.f = lo; b.f = hi;
    return __builtin_amdgcn_perm(b.u + 0x8000u, a.u + 0x8000u, 0x07060302u);
}

// =====================================================================
// Pre-pass A: cast X fp32 -> bf16
// =====================================================================
__global__ __launch_bounds__(256) void cast_x_kernel(
    const float* __restrict__ X, unsigned short* __restrict__ Xb)
{
    const size_t i = ((size_t)blockIdx.x * 256 + threadIdx.x) * 8;
    const float4 a = *(const float4*)(X + i);
    const float4 b = *(const float4*)(X + i + 4);
    u16x8 o;
    o[0] = f2bf(a.x); o[1] = f2bf(a.y); o[2] = f2bf(a.z); o[3] = f2bf(a.w);
    o[4] = f2bf(b.x); o[5] = f2bf(b.y); o[6] = f2bf(b.z); o[7] = f2bf(b.w);
    *(u16x8*)(Xb + i) = o;
}

// =====================================================================
// Pre-pass B: transpose-cast W [K][N] fp32 -> Wt [N][K] bf16
// =====================================================================
__global__ __launch_bounds__(256) void tcast_kernel(
    const float* __restrict__ src, unsigned short* __restrict__ dst,
    int K, int N)
{
    __shared__ float ts[32][33];
    const int t = threadIdx.x;
    const int n0 = blockIdx.x * 32, k0 = blockIdx.y * 32;
    const int r = t >> 5, c = t & 31;
    #pragma unroll
    for (int p = 0; p < 4; ++p)
        ts[r + p * 8][c] = src[(size_t)(k0 + r + p * 8) * N + n0 + c];
    __syncthreads();
    #pragma unroll
    for (int p = 0; p < 4; ++p)
        dst[(size_t)(n0 + r + p * 8) * K + k0 + c] = f2bf(ts[c][r + p * 8]);
}

// =====================================================================
// Kernel 1: QKV projection via bf16 MFMA + fused RoPE + head-split.
// =====================================================================
__global__ __launch_bounds__(256) void proj_qkv_mfma(
    const unsigned short* __restrict__ Xb, const unsigned short* __restrict__ Wt,
    unsigned short* __restrict__ qb, unsigned short* __restrict__ kb,
    unsigned short* __restrict__ vb)
{
    __shared__ __align__(16) unsigned short As[128 * 32];
    __shared__ __align__(16) unsigned short Bs[128 * 32];

    const int t     = threadIdx.x;
    const int w     = t >> 6, lane = t & 63;
    const int lane4 = lane & 15, quad = lane >> 4, quad8 = quad * 8;
    const int wm    = w >> 1, wn = w & 1;
    const int m0    = blockIdx.y * 128, n0 = blockIdx.x * 128;

    const int srow = t >> 2, scol = (t & 3) * 8;
    const unsigned short* gA = Xb + (size_t)(m0 + srow) * DD + scol;
    const unsigned short* gB = Wt + (size_t)(n0 + srow) * DD + scol;
    unsigned short* lA = As + t * 8;
    unsigned short* lB = Bs + t * 8;

    f32x4 acc[4][4] = {};

    for (int k0 = 0; k0 < DD; k0 += 32) {
        __syncthreads();
        ASYNC16(gA + k0,            lA);
        ASYNC16(gA + 64 * DD + k0,  lA + 2048);
        ASYNC16(gB + k0,            lB);
        ASYNC16(gB + 64 * DD + k0,  lB + 2048);
        __syncthreads();

        bf16x8 a[4], b[4];
        #pragma unroll
        for (int i = 0; i < 4; ++i)
            a[i] = *(const bf16x8*)&As[(wm * 64 + i * 16 + lane4) * 32 + quad8];
        #pragma unroll
        for (int j = 0; j < 4; ++j)
            b[j] = *(const bf16x8*)&Bs[(wn * 64 + j * 16 + lane4) * 32 + quad8];
        #pragma unroll
        for (int i = 0; i < 4; ++i)
            #pragma unroll
            for (int j = 0; j < 4; ++j)
                acc[i][j] = MFMA16(a[i], b[j], acc[i][j]);
    }

    // ---- epilogue ----
    const int sec = n0 >> 10;                  // 0=q 1=k 2=v (uniform/block)

    if (sec == 2) {
        // V: transposed global layout, 4 consecutive n per lane -> uint2
        #pragma unroll
        for (int j = 0; j < 4; ++j) {
            const int csec = (n0 & 1023) + wn * 64 + j * 16;
            const int h    = csec >> 6;
            const int dh   = (csec & 63) + lane4;
            #pragma unroll
            for (int i = 0; i < 4; ++i) {
                const int rg0 = m0 + wm * 64 + i * 16 + quad * 4;
                const int b   = rg0 >> 11;
                const int n   = rg0 & 2047;
                uint2 pk;
                pk.x = packbf2(acc[i][j][0], acc[i][j][1]);
                pk.y = packbf2(acc[i][j][2], acc[i][j][3]);
                *(uint2*)(vb + (((size_t)b * HH + h) * DHD + dh) * NN + n) = pk;
            }
        }
    } else {
        unsigned short* dst = (sec == 0) ? qb : kb;
        const float qscale = (sec == 0) ? SCALE_LOG2E : 1.0f;
        #pragma unroll
        for (int j = 0; j < 4; ++j) {
            const int csec = (n0 & 1023) + wn * 64 + j * 16;
            const int h    = csec >> 6;
            const int dhb  = csec & 63;
            const int dh   = dhb + lane4;
            const bool rope = (dhb < 32);          // wave-uniform
            const float invf = fexp2(-(float)(dh >> 1) * LOG2_10K_D16);
            #pragma unroll
            for (int i = 0; i < 4; ++i) {
                #pragma unroll
                for (int r = 0; r < 4; ++r) {
                    const int rg = m0 + wm * 64 + i * 16 + quad * 4 + r;
                    const int b  = rg >> 11;
                    const int n  = rg & 2047;
                    float x = acc[i][j][r] * qscale;
                    if (rope) {
                        const float ang = (float)n * invf;
                        float s_, c_;
                        __sincosf(ang, &s_, &c_);
                        const float p = __shfl_xor(x, 1);
                        x = (lane4 & 1) ? fmaf(p, s_, x * c_)
                                        : fmaf(p, -s_, x * c_);
                    }
                    dst[(((size_t)b * HH + h) * NN + n) * DHD + dh] = f2bf(x);
                }
            }
        }
    }
}

// =====================================================================
// Kernel 2: flash attention, KEY-SPLIT waves, SINGLE-buffer wave-private
// staging (R7 = R6 structure, spill-free occupancy target).
// R6 post-mortem: __launch_bounds__(256,5) forced VGPR 96->48 and
// spilled 3.1 GB to scratch (FETCH+WRITE counters). HW occupancy
// quantum (m69: waves halve at 64/128/256 VGPR) means 96-VGPR code
// gets 4 waves/SIMD anyway -> bound (256,4): budget 128 >= 96 live,
// zero spill, 4 blocks/CU (LDS 4x32=128 <= 160 KB).
// Structure: wave kq owns key-quarter; Q for all 64 queries in regs;
// P never leaves registers; single-buffer LDS is race-free since
// staging is wave-private and per-wave DS ops are in-order. No
// barriers in the main loop; 4 waves/SIMD hide the serial chain.
// XCD pinning kept: id%8 == bh%8 -> K/V L2-resident.
// =====================================================================
__global__ __launch_bounds__(256, 4) void attn_kernel(
    const unsigned short* __restrict__ qb, const unsigned short* __restrict__ kb,
    const unsigned short* __restrict__ vtb, unsigned short* __restrict__ aob)
{
    __shared__ __align__(16) unsigned char smem[32768];
    unsigned short (*ks)[64]  = (unsigned short (*)[64])smem;            // [128][64]  16KB
    unsigned short (*vs)[128] = (unsigned short (*)[128])(smem + 16384); // [64][128]  16KB

    const int t     = threadIdx.x;
    const int kq    = t >> 6;          // wave's key-quarter
    const int lane  = t & 63;
    const int lane4 = lane & 15;
    const int quad  = lane >> 4;
    const int quad8 = quad * 8;
    const int l7    = lane4 & 7;

    const int bid = blockIdx.x;
    const int bh  = bid & 63;          // id%8 = bh%8 -> per-XCD head groups
    const int q0  = (bid >> 6) * 64;
    const size_t hb = (size_t)bh * NN * DHD;

    // Q B-fragments for ALL 64 queries (held in registers whole kernel)
    bf16x8 qf[4][2];
    #pragma unroll
    for (int qt = 0; qt < 4; ++qt) {
        const unsigned short* qrow = qb + hb + (size_t)(q0 + qt * 16 + lane4) * DHD;
        qf[qt][0] = *(const bf16x8*)(qrow + quad8);
        qf[qt][1] = *(const bf16x8*)(qrow + 32 + quad8);
    }

    // ones A-fragment for the l-accumulating MFMA
    bf16x8 onesf;
    #pragma unroll
    for (int j = 0; j < 8; ++j) onesf[j] = (short)0x3F80;

    // ---- wave-private staging maps (each wave stages ONLY its keys) ----
    // K: 4 chunks, rows (within tile) = kq*16 + (lane>>3) + {0, 8, 64, 72},
    //    global col (lane&7)*8, LDS slot (lane&7)^(lane>>3) (row&7 == lane>>3)
    const int krow  = kq * 16 + (lane >> 3);
    const int kslot = ((lane & 7) ^ (lane >> 3)) * 8;
    const unsigned short* kg = kb + hb + (size_t)krow * DHD + (lane & 7) * 8;

    // V: 4 chunks s=0..3, rows = (lane>>2) + 16*s, key-group
    //    vm = 2kq + (lane&1) + ((lane>>1)&1)*8  (wave's 4 of 16 groups);
    //    8 keys -> logical slots (vm&7)*2 (lo4) and (vm&7)*2+1 (hi4),
    //    half-offset (vm>>3)*4, physical slot XOR row&7 (== vrow0&7).
    const int vrow0 = lane >> 2;
    const int vm    = 2 * kq + (lane & 1) + ((lane >> 1) & 1) * 8;
    const int vr7   = vrow0 & 7;
    const int halfo = (vm >> 3) * 4;
    const int colA  = ((((vm & 7) * 2)     ^ vr7) * 8) + halfo;
    const int colB  = ((((vm & 7) * 2 + 1) ^ vr7) * 8) + halfo;
    const unsigned short* vg = vtb + hb + (size_t)vrow0 * NN + vm * 8;

    f32x4 o[4][4], lacc[4];
    #pragma unroll
    for (int d = 0; d < 4; ++d)
        #pragma unroll
        for (int qt = 0; qt < 4; ++qt) o[d][qt] = (f32x4){0.f, 0.f, 0.f, 0.f};
    #pragma unroll
    for (int qt = 0; qt < 4; ++qt) lacc[qt] = (f32x4){0.f, 0.f, 0.f, 0.f};

    // ---- prologue: stage tile 0 (wave-private, no barrier) ----
    {
        const bf16x8 k0 = *(const bf16x8*)(kg);
        const bf16x8 k1 = *(const bf16x8*)(kg + 8 * DHD);
        const bf16x8 k2 = *(const bf16x8*)(kg + 64 * DHD);
        const bf16x8 k3 = *(const bf16x8*)(kg + 72 * DHD);
        const bf16x8 v0 = *(const bf16x8*)(vg);
        const bf16x8 v1 = *(const bf16x8*)(vg + (size_t)16 * NN);
        const bf16x8 v2 = *(const bf16x8*)(vg + (size_t)32 * NN);
        const bf16x8 v3 = *(const bf16x8*)(vg + (size_t)48 * NN);
        *(bf16x8*)&ks[krow][kslot]      = k0;
        *(bf16x8*)&ks[krow + 8][kslot]  = k1;
        *(bf16x8*)&ks[krow + 64][kslot] = k2;
        *(bf16x8*)&ks[krow + 72][kslot] = k3;
        #pragma unroll
        for (int s = 0; s < 4; ++s) {
            const bf16x8 vv = (s == 0) ? v0 : (s == 1) ? v1 : (s == 2) ? v2 : v3;
            bf16x4 lo = __builtin_shufflevector(vv, vv, 0, 1, 2, 3);
            bf16x4 hi = __builtin_shufflevector(vv, vv, 4, 5, 6, 7);
            *(bf16x4*)&vs[vrow0 + 16 * s][colA] = lo;
            *(bf16x4*)&vs[vrow0 + 16 * s][colB] = hi;
        }
    }

    for (int kt = 0; kt < NN / 128; ++kt) {
        const bool more = (kt + 1 < NN / 128);

        // ---- issue next tile's global loads (latency hides under compute) ----
        bf16x8 nk0, nk1, nk2, nk3, nv0, nv1, nv2, nv3;
        if (more) {
            const unsigned short* kgn = kg + (size_t)(kt + 1) * 128 * DHD;
            const unsigned short* vgn = vg + (kt + 1) * 128;
            nk0 = *(const bf16x8*)(kgn);
            nk1 = *(const bf16x8*)(kgn + 8 * DHD);
            nk2 = *(const bf16x8*)(kgn + 64 * DHD);
            nk3 = *(const bf16x8*)(kgn + 72 * DHD);
            nv0 = *(const bf16x8*)(vgn);
            nv1 = *(const bf16x8*)(vgn + (size_t)16 * NN);
            nv2 = *(const bf16x8*)(vgn + (size_t)32 * NN);
            nv3 = *(const bf16x8*)(vgn + (size_t)48 * NN);
        }

        // ---- QK A-fragments: this wave's 16 keys per 64-key subtile ----
        bf16x8 ak[2][2];
        #pragma unroll
        for (int sub = 0; sub < 2; ++sub) {
            const int row = sub * 64 + kq * 16 + lane4;
            ak[sub][0] = *(const bf16x8*)&ks[row][(quad ^ l7) * 8];
            ak[sub][1] = *(const bf16x8*)&ks[row][((quad + 4) ^ l7) * 8];
        }

        // ---- S^T -> exp2 -> P B-frags, all in registers ----
        bf16x8 pb[4];
        #pragma unroll
        for (int qt = 0; qt < 4; ++qt) {
            f32x4 z0 = (f32x4){0.f, 0.f, 0.f, 0.f};
            f32x4 z1 = (f32x4){0.f, 0.f, 0.f, 0.f};
            z0 = MFMA16(ak[0][0], qf[qt][0], z0);
            z0 = MFMA16(ak[0][1], qf[qt][1], z0);
            z1 = MFMA16(ak[1][0], qf[qt][0], z1);
            z1 = MFMA16(ak[1][1], qf[qt][1], z1);
            union { unsigned int u[4]; bf16x8 v; } pk;
            pk.u[0] = packbf2(fexp2(z0[0]), fexp2(z0[1]));
            pk.u[1] = packbf2(fexp2(z0[2]), fexp2(z0[3]));
            pk.u[2] = packbf2(fexp2(z1[0]), fexp2(z1[1]));
            pk.u[3] = packbf2(fexp2(z1[2]), fexp2(z1[3]));
            pb[qt] = pk.v;
            lacc[qt] = MFMA16(onesf, pb[qt], lacc[qt]);   // l partial (wave's keys)
        }

        // ---- O^T += V^T P^T over this wave's 32 keys ----
        #pragma unroll
        for (int d = 0; d < 4; ++d) {
            const bf16x8 av = *(const bf16x8*)&vs[d * 16 + lane4][((kq * 4 + quad) ^ l7) * 8];
            #pragma unroll
            for (int qt = 0; qt < 4; ++qt)
                o[d][qt] = MFMA16(av, pb[qt], o[d][qt]);
        }

        // ---- write-late: staged regs -> SAME buffer (in-order DS per wave
        //      guarantees this tile's reads were served first) ----
        if (more) {
            *(bf16x8*)&ks[krow][kslot]      = nk0;
            *(bf16x8*)&ks[krow + 8][kslot]  = nk1;
            *(bf16x8*)&ks[krow + 64][kslot] = nk2;
            *(bf16x8*)&ks[krow + 72][kslot] = nk3;
            #pragma unroll
            for (int s = 0; s < 4; ++s) {
                const bf16x8 vv = (s == 0) ? nv0 : (s == 1) ? nv1 : (s == 2) ? nv2 : nv3;
                bf16x4 lo = __builtin_shufflevector(vv, vv, 0, 1, 2, 3);
                bf16x4 hi = __builtin_shufflevector(vv, vv, 4, 5, 6, 7);
                *(bf16x4*)&vs[vrow0 + 16 * s][colA] = lo;
                *(bf16x4*)&vs[vrow0 + 16 * s][colB] = hi;
            }
        }
        // NO barrier in the main loop
    }

    // ---- epilogue: cross-wave O reduction, two-phase 32 KB overlay ----
    // pbuf[i][dh][col], i in {0,1}; col XOR-swizzled by writer quad
    // (derivable from dh: (dh>>2)&3 == quad) to avoid 4-way conflicts.
    __syncthreads();   // all waves done with ks/vs
    float* pbuf = (float*)smem;   // [2][64][64] f32 = 32 KB

    if (kq < 2) {
        // phase A: waves 0,1 write their partials to slab kq
        #pragma unroll
        for (int d = 0; d < 4; ++d)
            #pragma unroll
            for (int qt = 0; qt < 4; ++qt) {
                const int col = (qt * 16 + lane4) ^ (quad << 4);
                #pragma unroll
                for (int r = 0; r < 4; ++r) {
                    const int dh = d * 16 + quad * 4 + r;
                    pbuf[(kq * 64 + dh) * 64 + col] = o[d][qt][r];
                }
            }
    }
    __syncthreads();
    if (kq >= 2) {
        // phase B: waves 2,3 accumulate into slab kq-2
        #pragma unroll
        for (int d = 0; d < 4; ++d)
            #pragma unroll
            for (int qt = 0; qt < 4; ++qt) {
                const int col = (qt * 16 + lane4) ^ (quad << 4);
                #pragma unroll
                for (int r = 0; r < 4; ++r) {
                    const int dh = d * 16 + quad * 4 + r;
                    const int idx = ((kq - 2) * 64 + dh) * 64 + col;
                    pbuf[idx] += o[d][qt][r];
                }
            }
    }
    __syncthreads();

    // phase C: wave kq finalizes q-tile kq (all dh)
    f32x4 of[4];
    {
        const int qcol = (kq * 16 + lane4) ^ (quad << 4);
        #pragma unroll
        for (int d = 0; d < 4; ++d)
            #pragma unroll
            for (int r = 0; r < 4; ++r) {
                const int dh = d * 16 + quad * 4 + r;
                of[d][r] = pbuf[dh * 64 + qcol] + pbuf[(64 + dh) * 64 + qcol];
            }
    }
    __syncthreads();

    // l exchange (reuse first 1 KB of the overlay after O is consumed)
    if (quad == 0) {
        #pragma unroll
        for (int qt = 0; qt < 4; ++qt)
            pbuf[(kq * 4 + qt) * 16 + lane4] = lacc[qt][0];
    }
    __syncthreads();
    const float lt = pbuf[(0 * 4 + kq) * 16 + lane4] + pbuf[(1 * 4 + kq) * 16 + lane4]
                   + pbuf[(2 * 4 + kq) * 16 + lane4] + pbuf[(3 * 4 + kq) * 16 + lane4];
    const float linv = 1.0f / lt;

    const int b = bh >> 4, h = bh & 15;
    const int n = q0 + kq * 16 + lane4;
    unsigned short* obase = aob + ((size_t)b * NN + n) * INNER + h * DHD;
    #pragma unroll
    for (int d = 0; d < 4; ++d) {
        uint2 pk;
        pk.x = packbf2(of[d][0] * linv, of[d][1] * linv);
        pk.y = packbf2(of[d][2] * linv, of[d][3] * linv);
        *(uint2*)(obase + d * 16 + quad * 4) = pk;
    }
}

// =====================================================================
// Kernel 3: output projection via bf16 MFMA.
// =====================================================================
__global__ __launch_bounds__(256) void out_proj_mfma(
    const unsigned short* __restrict__ Ab, const unsigned short* __restrict__ Wt,
    const float* __restrict__ bias, float* __restrict__ C)
{
    __shared__ __align__(16) unsigned short As[128 * 32];
    __shared__ __align__(16) unsigned short Bs[128 * 32];

    const int t     = threadIdx.x;
    const int w     = t >> 6, lane = t & 63;
    const int lane4 = lane & 15, quad = lane >> 4, quad8 = quad * 8;
    const int wm    = w >> 1, wn = w & 1;
    const int m0    = blockIdx.y * 128, n0 = blockIdx.x * 128;

    const int srow = t >> 2, scol = (t & 3) * 8;
    const unsigned short* gA = Ab + (size_t)(m0 + srow) * INNER + scol;
    const unsigned short* gB = Wt + (size_t)(n0 + srow) * INNER + scol;
    unsigned short* lA = As + t * 8;
    unsigned short* lB = Bs + t * 8;

    f32x4 acc[4][4] = {};

    for (int k0 = 0; k0 < INNER; k0 += 32) {
        __syncthreads();
        ASYNC16(gA + k0,               lA);
        ASYNC16(gA + 64 * INNER + k0,  lA + 2048);
        ASYNC16(gB + k0,               lB);
        ASYNC16(gB + 64 * INNER + k0,  lB + 2048);
        __syncthreads();

        bf16x8 a[4], b[4];
        #pragma unroll
        for (int i = 0; i < 4; ++i)
            a[i] = *(const bf16x8*)&As[(wm * 64 + i * 16 + lane4) * 32 + quad8];
        #pragma unroll
        for (int j = 0; j < 4; ++j)
            b[j] = *(const bf16x8*)&Bs[(wn * 64 + j * 16 + lane4) * 32 + quad8];
        #pragma unroll
        for (int i = 0; i < 4; ++i)
            #pragma unroll
            for (int j = 0; j < 4; ++j)
                acc[i][j] = MFMA16(a[i], b[j], acc[i][j]);
    }

    #pragma unroll
    for (int j = 0; j < 4; ++j) {
        const int col = n0 + wn * 64 + j * 16 + lane4;
        const float bv = bias[col];
        #pragma unroll
        for (int i = 0; i < 4; ++i)
            #pragma unroll
            for (int r = 0; r < 4; ++r) {
                const int rg = m0 + wm * 64 + i * 16 + quad * 4 + r;
                C[(size_t)rg * DD + col] = acc[i][j][r] + bv;
            }
    }
}

// =====================================================================
extern "C" void kernel_launch(void* const* d_in, const int* in_sizes, int n_in,
                              void* d_out, int out_size, void* d_ws, size_t ws_size,
                              hipStream_t stream)
{
    const float* X    = (const float*)d_in[0];   // (4,2048,1024)
    const float* Wq   = (const float*)d_in[1];   // (1024,1024)
    const float* Wkv  = (const float*)d_in[2];   // (1024,2048)
    const float* Wout = (const float*)d_in[3];   // (1024,1024)
    const float* bout = (const float*)d_in[4];   // (1024,)
    float* out = (float*)d_out;

    // ws (bf16 elems): qb|kb|vtb|xb(=aob after proj)|WtAll|WoT = 75.5 MB
    const size_t E = (size_t)BB * HH * NN * DHD;   // 8388608
    unsigned short* qb  = (unsigned short*)d_ws;
    unsigned short* kb  = qb + E;
    unsigned short* vtb = kb + E;                // V^T [b][h][dh][n]
    unsigned short* xb  = vtb + E;               // X bf16; later reused as ao
    unsigned short* wt  = xb + E;                // [3072][1024] = WqT ; WkvT
    unsigned short* wo  = wt + (size_t)3072 * 1024;  // [1024][1024]

    cast_x_kernel<<<4096, 256, 0, stream>>>(X, xb);
    tcast_kernel<<<dim3(32, 32), 256, 0, stream>>>(Wq,   wt,               1024, 1024);
    tcast_kernel<<<dim3(64, 32), 256, 0, stream>>>(Wkv,  wt + 1024 * 1024, 1024, 2048);
    tcast_kernel<<<dim3(32, 32), 256, 0, stream>>>(Wout, wo,               1024, 1024);

    proj_qkv_mfma<<<dim3(3072 / 128, 8192 / 128), 256, 0, stream>>>(
        xb, wt, qb, kb, vtb);

    attn_kernel<<<dim3(NN / 64 * BB * HH), 256, 0, stream>>>(qb, kb, vtb, xb);

    out_proj_mfma<<<dim3(1024 / 128, 8192 / 128), 256, 0, stream>>>(
        xb, wo, bout, out);
}

// Round 8
// 317.328 us; speedup vs baseline: 2.7757x; 2.1828x over previous
//
#include <hip/hip_runtime.h>
#include <math.h>

// Problem constants (fixed by reference: b=4, n=2048, d=1024, H=16, DH=64)
#define BB    4
#define NN    2048
#define DD    1024
#define HH    16
#define DHD   64
#define INNER 1024
// log2(10000)/16 for inv_freq = 2^(-f * LOG2_10K_D16)
#define LOG2_10K_D16 0.8304820237218406f
// SCALE * log2(e): folded into Q at projection time -> attn uses raw exp2
#define SCALE_LOG2E 0.1803368801111601f

typedef short bf16x8 __attribute__((ext_vector_type(8)));   // 8 bf16 = 4 VGPRs
typedef short bf16x4 __attribute__((ext_vector_type(4)));   // 4 bf16 = 2 VGPRs
typedef float f32x4  __attribute__((ext_vector_type(4)));
typedef unsigned short u16x8 __attribute__((ext_vector_type(8)));

// async 16B/lane global->LDS (lane i lands at wave-uniform base + i*16)
#define ASYNC16(g, l) __builtin_amdgcn_global_load_lds( \
    (const __attribute__((address_space(1))) void*)(g),  \
    (__attribute__((address_space(3))) void*)(l), 16, 0, 0)

#define MFMA16(a, b, c) __builtin_amdgcn_mfma_f32_16x16x32_bf16((a), (b), (c), 0, 0, 0)

// ---------- fast exp2: raw v_exp_f32, no libm range guard ----------
static __device__ __forceinline__ float fexp2(float x) {
#if __has_builtin(__builtin_amdgcn_exp2f)
    return __builtin_amdgcn_exp2f(x);
#else
    float r;
    asm("v_exp_f32 %0, %1" : "=v"(r) : "v"(x));
    return r;
#endif
}

// ---------- bf16 helpers (manual RNE; no hip_bf16.h dependency) ----------
static __device__ __forceinline__ unsigned short f2bf(float f) {
    union { float f; unsigned int u; } v; v.f = f;
    unsigned int u = v.u;
    u += 0x7fffu + ((u >> 16) & 1u);
    return (unsigned short)(u >> 16);
}
// pack two f32 -> bf16x2 dword, round-half-up via +0x8000 then byte-perm.
static __device__ __forceinline__ unsigned int packbf2(float lo, float hi) {
    union { float f; unsigned int u; } a, b;
    a.f = lo; b.f = hi;
    return __builtin_amdgcn_perm(b.u + 0x8000u, a.u + 0x8000u, 0x07060302u);
}

// =====================================================================
// Pre-pass A: cast X fp32 -> bf16
// =====================================================================
__global__ __launch_bounds__(256) void cast_x_kernel(
    const float* __restrict__ X, unsigned short* __restrict__ Xb)
{
    const size_t i = ((size_t)blockIdx.x * 256 + threadIdx.x) * 8;
    const float4 a = *(const float4*)(X + i);
    const float4 b = *(const float4*)(X + i + 4);
    u16x8 o;
    o[0] = f2bf(a.x); o[1] = f2bf(a.y); o[2] = f2bf(a.z); o[3] = f2bf(a.w);
    o[4] = f2bf(b.x); o[5] = f2bf(b.y); o[6] = f2bf(b.z); o[7] = f2bf(b.w);
    *(u16x8*)(Xb + i) = o;
}

// =====================================================================
// Pre-pass B: transpose-cast W [K][N] fp32 -> Wt [N][K] bf16
// =====================================================================
__global__ __launch_bounds__(256) void tcast_kernel(
    const float* __restrict__ src, unsigned short* __restrict__ dst,
    int K, int N)
{
    __shared__ float ts[32][33];
    const int t = threadIdx.x;
    const int n0 = blockIdx.x * 32, k0 = blockIdx.y * 32;
    const int r = t >> 5, c = t & 31;
    #pragma unroll
    for (int p = 0; p < 4; ++p)
        ts[r + p * 8][c] = src[(size_t)(k0 + r + p * 8) * N + n0 + c];
    __syncthreads();
    #pragma unroll
    for (int p = 0; p < 4; ++p)
        dst[(size_t)(n0 + r + p * 8) * K + k0 + c] = f2bf(ts[c][r + p * 8]);
}

// =====================================================================
// Kernel 1: QKV projection via bf16 MFMA + fused RoPE + head-split.
// =====================================================================
__global__ __launch_bounds__(256) void proj_qkv_mfma(
    const unsigned short* __restrict__ Xb, const unsigned short* __restrict__ Wt,
    unsigned short* __restrict__ qb, unsigned short* __restrict__ kb,
    unsigned short* __restrict__ vb)
{
    __shared__ __align__(16) unsigned short As[128 * 32];
    __shared__ __align__(16) unsigned short Bs[128 * 32];

    const int t     = threadIdx.x;
    const int w     = t >> 6, lane = t & 63;
    const int lane4 = lane & 15, quad = lane >> 4, quad8 = quad * 8;
    const int wm    = w >> 1, wn = w & 1;
    const int m0    = blockIdx.y * 128, n0 = blockIdx.x * 128;

    const int srow = t >> 2, scol = (t & 3) * 8;
    const unsigned short* gA = Xb + (size_t)(m0 + srow) * DD + scol;
    const unsigned short* gB = Wt + (size_t)(n0 + srow) * DD + scol;
    unsigned short* lA = As + t * 8;
    unsigned short* lB = Bs + t * 8;

    f32x4 acc[4][4] = {};

    for (int k0 = 0; k0 < DD; k0 += 32) {
        __syncthreads();
        ASYNC16(gA + k0,            lA);
        ASYNC16(gA + 64 * DD + k0,  lA + 2048);
        ASYNC16(gB + k0,            lB);
        ASYNC16(gB + 64 * DD + k0,  lB + 2048);
        __syncthreads();

        bf16x8 a[4], b[4];
        #pragma unroll
        for (int i = 0; i < 4; ++i)
            a[i] = *(const bf16x8*)&As[(wm * 64 + i * 16 + lane4) * 32 + quad8];
        #pragma unroll
        for (int j = 0; j < 4; ++j)
            b[j] = *(const bf16x8*)&Bs[(wn * 64 + j * 16 + lane4) * 32 + quad8];
        #pragma unroll
        for (int i = 0; i < 4; ++i)
            #pragma unroll
            for (int j = 0; j < 4; ++j)
                acc[i][j] = MFMA16(a[i], b[j], acc[i][j]);
    }

    // ---- epilogue ----
    const int sec = n0 >> 10;                  // 0=q 1=k 2=v (uniform/block)

    if (sec == 2) {
        // V: transposed global layout, 4 consecutive n per lane -> uint2
        #pragma unroll
        for (int j = 0; j < 4; ++j) {
            const int csec = (n0 & 1023) + wn * 64 + j * 16;
            const int h    = csec >> 6;
            const int dh   = (csec & 63) + lane4;
            #pragma unroll
            for (int i = 0; i < 4; ++i) {
                const int rg0 = m0 + wm * 64 + i * 16 + quad * 4;
                const int b   = rg0 >> 11;
                const int n   = rg0 & 2047;
                uint2 pk;
                pk.x = packbf2(acc[i][j][0], acc[i][j][1]);
                pk.y = packbf2(acc[i][j][2], acc[i][j][3]);
                *(uint2*)(vb + (((size_t)b * HH + h) * DHD + dh) * NN + n) = pk;
            }
        }
    } else {
        unsigned short* dst = (sec == 0) ? qb : kb;
        const float qscale = (sec == 0) ? SCALE_LOG2E : 1.0f;
        #pragma unroll
        for (int j = 0; j < 4; ++j) {
            const int csec = (n0 & 1023) + wn * 64 + j * 16;
            const int h    = csec >> 6;
            const int dhb  = csec & 63;
            const int dh   = dhb + lane4;
            const bool rope = (dhb < 32);          // wave-uniform
            const float invf = fexp2(-(float)(dh >> 1) * LOG2_10K_D16);
            #pragma unroll
            for (int i = 0; i < 4; ++i) {
                #pragma unroll
                for (int r = 0; r < 4; ++r) {
                    const int rg = m0 + wm * 64 + i * 16 + quad * 4 + r;
                    const int b  = rg >> 11;
                    const int n  = rg & 2047;
                    float x = acc[i][j][r] * qscale;
                    if (rope) {
                        const float ang = (float)n * invf;
                        float s_, c_;
                        __sincosf(ang, &s_, &c_);
                        const float p = __shfl_xor(x, 1);
                        x = (lane4 & 1) ? fmaf(p, s_, x * c_)
                                        : fmaf(p, -s_, x * c_);
                    }
                    dst[(((size_t)b * HH + h) * NN + n) * DHD + dh] = f2bf(x);
                }
            }
        }
    }
}

// =====================================================================
// Kernel 2: flash attention, KEY-SPLIT waves, SINGLE-buffer wave-private
// staging (R8).
// R6/R7 post-mortem: allocator splits the wave budget into arch-VGPR
// + AGPR halves when MFMA accs are present; true live set ~176 regs
// (R4: 96 arch + ~80 acc) -> any bound under that spills GBs.
// R8: shave 20 regs so 3 waves/SIMD genuinely fits:
//   - l-accumulating MFMA (lacc f32x4[4]=16 + onesf=4) replaced by
//     f32 VALU sums of the exp outputs (lsum[4], 32 adds/iter) +
//     one-time cross-quad __shfl_xor reduce. Also -4 MFMA/iter and
//     a MORE accurate denominator (f32 pre-round).
//   - total ~156 <= 168 = (256,3) budget -> no spill, 3 blocks/CU
//     (LDS 3x32=96 <= 160 KB).
// Structure: wave kq owns key-quarter; Q for all 64 queries in regs;
// P never leaves registers; single-buffer LDS race-free (wave-private
// staging + per-wave in-order DS). No main-loop barriers.
// XCD pinning kept: id%8 == bh%8 -> K/V L2-resident.
// =====================================================================
__global__ __launch_bounds__(256, 3) void attn_kernel(
    const unsigned short* __restrict__ qb, const unsigned short* __restrict__ kb,
    const unsigned short* __restrict__ vtb, unsigned short* __restrict__ aob)
{
    __shared__ __align__(16) unsigned char smem[32768];
    unsigned short (*ks)[64]  = (unsigned short (*)[64])smem;            // [128][64]  16KB
    unsigned short (*vs)[128] = (unsigned short (*)[128])(smem + 16384); // [64][128]  16KB

    const int t     = threadIdx.x;
    const int kq    = t >> 6;          // wave's key-quarter
    const int lane  = t & 63;
    const int lane4 = lane & 15;
    const int quad  = lane >> 4;
    const int quad8 = quad * 8;
    const int l7    = lane4 & 7;

    const int bid = blockIdx.x;
    const int bh  = bid & 63;          // id%8 = bh%8 -> per-XCD head groups
    const int q0  = (bid >> 6) * 64;
    const size_t hb = (size_t)bh * NN * DHD;

    // Q B-fragments for ALL 64 queries (held in registers whole kernel)
    bf16x8 qf[4][2];
    #pragma unroll
    for (int qt = 0; qt < 4; ++qt) {
        const unsigned short* qrow = qb + hb + (size_t)(q0 + qt * 16 + lane4) * DHD;
        qf[qt][0] = *(const bf16x8*)(qrow + quad8);
        qf[qt][1] = *(const bf16x8*)(qrow + 32 + quad8);
    }

    // ---- wave-private staging maps (each wave stages ONLY its keys) ----
    // K: 4 chunks, rows (within tile) = kq*16 + (lane>>3) + {0, 8, 64, 72},
    //    global col (lane&7)*8, LDS slot (lane&7)^(lane>>3) (row&7 == lane>>3)
    const int krow  = kq * 16 + (lane >> 3);
    const int kslot = ((lane & 7) ^ (lane >> 3)) * 8;
    const unsigned short* kg = kb + hb + (size_t)krow * DHD + (lane & 7) * 8;

    // V: 4 chunks s=0..3, rows = (lane>>2) + 16*s, key-group
    //    vm = 2kq + (lane&1) + ((lane>>1)&1)*8  (wave's 4 of 16 groups);
    //    8 keys -> logical slots (vm&7)*2 (lo4) and (vm&7)*2+1 (hi4),
    //    half-offset (vm>>3)*4, physical slot XOR row&7 (== vrow0&7).
    const int vrow0 = lane >> 2;
    const int vm    = 2 * kq + (lane & 1) + ((lane >> 1) & 1) * 8;
    const int vr7   = vrow0 & 7;
    const int halfo = (vm >> 3) * 4;
    const int colA  = ((((vm & 7) * 2)     ^ vr7) * 8) + halfo;
    const int colB  = ((((vm & 7) * 2 + 1) ^ vr7) * 8) + halfo;
    const unsigned short* vg = vtb + hb + (size_t)vrow0 * NN + vm * 8;

    f32x4 o[4][4];
    float lsum[4] = {0.f, 0.f, 0.f, 0.f};
    #pragma unroll
    for (int d = 0; d < 4; ++d)
        #pragma unroll
        for (int qt = 0; qt < 4; ++qt) o[d][qt] = (f32x4){0.f, 0.f, 0.f, 0.f};

    // ---- prologue: stage tile 0 (wave-private, no barrier) ----
    {
        const bf16x8 k0 = *(const bf16x8*)(kg);
        const bf16x8 k1 = *(const bf16x8*)(kg + 8 * DHD);
        const bf16x8 k2 = *(const bf16x8*)(kg + 64 * DHD);
        const bf16x8 k3 = *(const bf16x8*)(kg + 72 * DHD);
        const bf16x8 v0 = *(const bf16x8*)(vg);
        const bf16x8 v1 = *(const bf16x8*)(vg + (size_t)16 * NN);
        const bf16x8 v2 = *(const bf16x8*)(vg + (size_t)32 * NN);
        const bf16x8 v3 = *(const bf16x8*)(vg + (size_t)48 * NN);
        *(bf16x8*)&ks[krow][kslot]      = k0;
        *(bf16x8*)&ks[krow + 8][kslot]  = k1;
        *(bf16x8*)&ks[krow + 64][kslot] = k2;
        *(bf16x8*)&ks[krow + 72][kslot] = k3;
        #pragma unroll
        for (int s = 0; s < 4; ++s) {
            const bf16x8 vv = (s == 0) ? v0 : (s == 1) ? v1 : (s == 2) ? v2 : v3;
            bf16x4 lo = __builtin_shufflevector(vv, vv, 0, 1, 2, 3);
            bf16x4 hi = __builtin_shufflevector(vv, vv, 4, 5, 6, 7);
            *(bf16x4*)&vs[vrow0 + 16 * s][colA] = lo;
            *(bf16x4*)&vs[vrow0 + 16 * s][colB] = hi;
        }
    }

    for (int kt = 0; kt < NN / 128; ++kt) {
        const bool more = (kt + 1 < NN / 128);

        // ---- issue next tile's global loads (latency hides under compute) ----
        bf16x8 nk0, nk1, nk2, nk3, nv0, nv1, nv2, nv3;
        if (more) {
            const unsigned short* kgn = kg + (size_t)(kt + 1) * 128 * DHD;
            const unsigned short* vgn = vg + (kt + 1) * 128;
            nk0 = *(const bf16x8*)(kgn);
            nk1 = *(const bf16x8*)(kgn + 8 * DHD);
            nk2 = *(const bf16x8*)(kgn + 64 * DHD);
            nk3 = *(const bf16x8*)(kgn + 72 * DHD);
            nv0 = *(const bf16x8*)(vgn);
            nv1 = *(const bf16x8*)(vgn + (size_t)16 * NN);
            nv2 = *(const bf16x8*)(vgn + (size_t)32 * NN);
            nv3 = *(const bf16x8*)(vgn + (size_t)48 * NN);
        }

        // ---- QK A-fragments: this wave's 16 keys per 64-key subtile ----
        bf16x8 ak[2][2];
        #pragma unroll
        for (int sub = 0; sub < 2; ++sub) {
            const int row = sub * 64 + kq * 16 + lane4;
            ak[sub][0] = *(const bf16x8*)&ks[row][(quad ^ l7) * 8];
            ak[sub][1] = *(const bf16x8*)&ks[row][((quad + 4) ^ l7) * 8];
        }

        // ---- S^T -> exp2 -> P B-frags, all in registers; l in f32 VALU ----
        bf16x8 pb[4];
        #pragma unroll
        for (int qt = 0; qt < 4; ++qt) {
            f32x4 z0 = (f32x4){0.f, 0.f, 0.f, 0.f};
            f32x4 z1 = (f32x4){0.f, 0.f, 0.f, 0.f};
            z0 = MFMA16(ak[0][0], qf[qt][0], z0);
            z0 = MFMA16(ak[0][1], qf[qt][1], z0);
            z1 = MFMA16(ak[1][0], qf[qt][0], z1);
            z1 = MFMA16(ak[1][1], qf[qt][1], z1);
            const float e00 = fexp2(z0[0]), e01 = fexp2(z0[1]);
            const float e02 = fexp2(z0[2]), e03 = fexp2(z0[3]);
            const float e10 = fexp2(z1[0]), e11 = fexp2(z1[1]);
            const float e12 = fexp2(z1[2]), e13 = fexp2(z1[3]);
            union { unsigned int u[4]; bf16x8 v; } pk;
            pk.u[0] = packbf2(e00, e01);
            pk.u[1] = packbf2(e02, e03);
            pk.u[2] = packbf2(e10, e11);
            pk.u[3] = packbf2(e12, e13);
            pb[qt] = pk.v;
            lsum[qt] += ((e00 + e01) + (e02 + e03)) + ((e10 + e11) + (e12 + e13));
        }

        // ---- O^T += V^T P^T over this wave's 32 keys ----
        #pragma unroll
        for (int d = 0; d < 4; ++d) {
            const bf16x8 av = *(const bf16x8*)&vs[d * 16 + lane4][((kq * 4 + quad) ^ l7) * 8];
            #pragma unroll
            for (int qt = 0; qt < 4; ++qt)
                o[d][qt] = MFMA16(av, pb[qt], o[d][qt]);
        }

        // ---- write-late: staged regs -> SAME buffer (in-order DS per wave
        //      guarantees this tile's reads were served first) ----
        if (more) {
            *(bf16x8*)&ks[krow][kslot]      = nk0;
            *(bf16x8*)&ks[krow + 8][kslot]  = nk1;
            *(bf16x8*)&ks[krow + 64][kslot] = nk2;
            *(bf16x8*)&ks[krow + 72][kslot] = nk3;
            #pragma unroll
            for (int s = 0; s < 4; ++s) {
                const bf16x8 vv = (s == 0) ? nv0 : (s == 1) ? nv1 : (s == 2) ? nv2 : nv3;
                bf16x4 lo = __builtin_shufflevector(vv, vv, 0, 1, 2, 3);
                bf16x4 hi = __builtin_shufflevector(vv, vv, 4, 5, 6, 7);
                *(bf16x4*)&vs[vrow0 + 16 * s][colA] = lo;
                *(bf16x4*)&vs[vrow0 + 16 * s][colB] = hi;
            }
        }
        // NO barrier in the main loop
    }

    // ---- cross-quad l reduce: lane (lane4,quad) holds quad's key-share ----
    #pragma unroll
    for (int qt = 0; qt < 4; ++qt) {
        float v = lsum[qt];
        v += __shfl_xor(v, 16);
        v += __shfl_xor(v, 32);
        lsum[qt] = v;          // full l over this wave's keys, all lanes
    }

    // ---- epilogue: cross-wave O reduction, two-phase 32 KB overlay ----
    // pbuf[i][dh][col], i in {0,1}; col XOR-swizzled by writer quad
    // (derivable from dh: (dh>>2)&3 == quad) to avoid 4-way conflicts.
    __syncthreads();   // all waves done with ks/vs
    float* pbuf = (float*)smem;   // [2][64][64] f32 = 32 KB

    if (kq < 2) {
        // phase A: waves 0,1 write their partials to slab kq
        #pragma unroll
        for (int d = 0; d < 4; ++d)
            #pragma unroll
            for (int qt = 0; qt < 4; ++qt) {
                const int col = (qt * 16 + lane4) ^ (quad << 4);
                #pragma unroll
                for (int r = 0; r < 4; ++r) {
                    const int dh = d * 16 + quad * 4 + r;
                    pbuf[(kq * 64 + dh) * 64 + col] = o[d][qt][r];
                }
            }
    }
    __syncthreads();
    if (kq >= 2) {
        // phase B: waves 2,3 accumulate into slab kq-2
        #pragma unroll
        for (int d = 0; d < 4; ++d)
            #pragma unroll
            for (int qt = 0; qt < 4; ++qt) {
                const int col = (qt * 16 + lane4) ^ (quad << 4);
                #pragma unroll
                for (int r = 0; r < 4; ++r) {
                    const int dh = d * 16 + quad * 4 + r;
                    const int idx = ((kq - 2) * 64 + dh) * 64 + col;
                    pbuf[idx] += o[d][qt][r];
                }
            }
    }
    __syncthreads();

    // phase C: wave kq finalizes q-tile kq (all dh)
    f32x4 of[4];
    {
        const int qcol = (kq * 16 + lane4) ^ (quad << 4);
        #pragma unroll
        for (int d = 0; d < 4; ++d)
            #pragma unroll
            for (int r = 0; r < 4; ++r) {
                const int dh = d * 16 + quad * 4 + r;
                of[d][r] = pbuf[dh * 64 + qcol] + pbuf[(64 + dh) * 64 + qcol];
            }
    }
    __syncthreads();

    // l exchange (reuse first 1 KB of the overlay after O is consumed)
    if (quad == 0) {
        #pragma unroll
        for (int qt = 0; qt < 4; ++qt)
            pbuf[(kq * 4 + qt) * 16 + lane4] = lsum[qt];
    }
    __syncthreads();
    const float lt = pbuf[(0 * 4 + kq) * 16 + lane4] + pbuf[(1 * 4 + kq) * 16 + lane4]
                   + pbuf[(2 * 4 + kq) * 16 + lane4] + pbuf[(3 * 4 + kq) * 16 + lane4];
    const float linv = 1.0f / lt;

    const int b = bh >> 4, h = bh & 15;
    const int n = q0 + kq * 16 + lane4;
    unsigned short* obase = aob + ((size_t)b * NN + n) * INNER + h * DHD;
    #pragma unroll
    for (int d = 0; d < 4; ++d) {
        uint2 pk;
        pk.x = packbf2(of[d][0] * linv, of[d][1] * linv);
        pk.y = packbf2(of[d][2] * linv, of[d][3] * linv);
        *(uint2*)(obase + d * 16 + quad * 4) = pk;
    }
}

// =====================================================================
// Kernel 3: output projection via bf16 MFMA.
// =====================================================================
__global__ __launch_bounds__(256) void out_proj_mfma(
    const unsigned short* __restrict__ Ab, const unsigned short* __restrict__ Wt,
    const float* __restrict__ bias, float* __restrict__ C)
{
    __shared__ __align__(16) unsigned short As[128 * 32];
    __shared__ __align__(16) unsigned short Bs[128 * 32];

    const int t     = threadIdx.x;
    const int w     = t >> 6, lane = t & 63;
    const int lane4 = lane & 15, quad = lane >> 4, quad8 = quad * 8;
    const int wm    = w >> 1, wn = w & 1;
    const int m0    = blockIdx.y * 128, n0 = blockIdx.x * 128;

    const int srow = t >> 2, scol = (t & 3) * 8;
    const unsigned short* gA = Ab + (size_t)(m0 + srow) * INNER + scol;
    const unsigned short* gB = Wt + (size_t)(n0 + srow) * INNER + scol;
    unsigned short* lA = As + t * 8;
    unsigned short* lB = Bs + t * 8;

    f32x4 acc[4][4] = {};

    for (int k0 = 0; k0 < INNER; k0 += 32) {
        __syncthreads();
        ASYNC16(gA + k0,               lA);
        ASYNC16(gA + 64 * INNER + k0,  lA + 2048);
        ASYNC16(gB + k0,               lB);
        ASYNC16(gB + 64 * INNER + k0,  lB + 2048);
        __syncthreads();

        bf16x8 a[4], b[4];
        #pragma unroll
        for (int i = 0; i < 4; ++i)
            a[i] = *(const bf16x8*)&As[(wm * 64 + i * 16 + lane4) * 32 + quad8];
        #pragma unroll
        for (int j = 0; j < 4; ++j)
            b[j] = *(const bf16x8*)&Bs[(wn * 64 + j * 16 + lane4) * 32 + quad8];
        #pragma unroll
        for (int i = 0; i < 4; ++i)
            #pragma unroll
            for (int j = 0; j < 4; ++j)
                acc[i][j] = MFMA16(a[i], b[j], acc[i][j]);
    }

    #pragma unroll
    for (int j = 0; j < 4; ++j) {
        const int col = n0 + wn * 64 + j * 16 + lane4;
        const float bv = bias[col];
        #pragma unroll
        for (int i = 0; i < 4; ++i)
            #pragma unroll
            for (int r = 0; r < 4; ++r) {
                const int rg = m0 + wm * 64 + i * 16 + quad * 4 + r;
                C[(size_t)rg * DD + col] = acc[i][j][r] + bv;
            }
    }
}

// =====================================================================
extern "C" void kernel_launch(void* const* d_in, const int* in_sizes, int n_in,
                              void* d_out, int out_size, void* d_ws, size_t ws_size,
                              hipStream_t stream)
{
    const float* X    = (const float*)d_in[0];   // (4,2048,1024)
    const float* Wq   = (const float*)d_in[1];   // (1024,1024)
    const float* Wkv  = (const float*)d_in[2];   // (1024,2048)
    const float* Wout = (const float*)d_in[3];   // (1024,1024)
    const float* bout = (const float*)d_in[4];   // (1024,)
    float* out = (float*)d_out;

    // ws (bf16 elems): qb|kb|vtb|xb(=aob after proj)|WtAll|WoT = 75.5 MB
    const size_t E = (size_t)BB * HH * NN * DHD;   // 8388608
    unsigned short* qb  = (unsigned short*)d_ws;
    unsigned short* kb  = qb + E;
    unsigned short* vtb = kb + E;                // V^T [b][h][dh][n]
    unsigned short* xb  = vtb + E;               // X bf16; later reused as ao
    unsigned short* wt  = xb + E;                // [3072][1024] = WqT ; WkvT
    unsigned short* wo  = wt + (size_t)3072 * 1024;  // [1024][1024]

    cast_x_kernel<<<4096, 256, 0, stream>>>(X, xb);
    tcast_kernel<<<dim3(32, 32), 256, 0, stream>>>(Wq,   wt,               1024, 1024);
    tcast_kernel<<<dim3(64, 32), 256, 0, stream>>>(Wkv,  wt + 1024 * 1024, 1024, 2048);
    tcast_kernel<<<dim3(32, 32), 256, 0, stream>>>(Wout, wo,               1024, 1024);

    proj_qkv_mfma<<<dim3(3072 / 128, 8192 / 128), 256, 0, stream>>>(
        xb, wt, qb, kb, vtb);

    attn_kernel<<<dim3(NN / 64 * BB * HH), 256, 0, stream>>>(qb, kb, vtb, xb);

    out_proj_mfma<<<dim3(1024 / 128, 8192 / 128), 256, 0, stream>>>(
        xb, wo, bout, out);
}

// Round 9
// 301.717 us; speedup vs baseline: 2.9193x; 1.0517x over previous
//
#include <hip/hip_runtime.h>
#include <math.h>

// Problem constants (fixed by reference: b=4, n=2048, d=1024, H=16, DH=64)
#define BB    4
#define NN    2048
#define DD    1024
#define HH    16
#define DHD   64
#define INNER 1024
// log2(10000)/16 for inv_freq = 2^(-f * LOG2_10K_D16)
#define LOG2_10K_D16 0.8304820237218406f
// SCALE * log2(e): folded into Q at projection time -> attn uses raw exp2
#define SCALE_LOG2E 0.1803368801111601f

typedef short bf16x8 __attribute__((ext_vector_type(8)));   // 8 bf16 = 4 VGPRs
typedef short bf16x4 __attribute__((ext_vector_type(4)));   // 4 bf16 = 2 VGPRs
typedef float f32x4  __attribute__((ext_vector_type(4)));
typedef unsigned short u16x8 __attribute__((ext_vector_type(8)));

// async 16B/lane global->LDS (lane i lands at wave-uniform base + i*16)
#define ASYNC16(g, l) __builtin_amdgcn_global_load_lds( \
    (const __attribute__((address_space(1))) void*)(g),  \
    (__attribute__((address_space(3))) void*)(l), 16, 0, 0)

#define MFMA16(a, b, c) __builtin_amdgcn_mfma_f32_16x16x32_bf16((a), (b), (c), 0, 0, 0)

// ---------- fast exp2: raw v_exp_f32, no libm range guard ----------
static __device__ __forceinline__ float fexp2(float x) {
#if __has_builtin(__builtin_amdgcn_exp2f)
    return __builtin_amdgcn_exp2f(x);
#else
    float r;
    asm("v_exp_f32 %0, %1" : "=v"(r) : "v"(x));
    return r;
#endif
}

// ---------- bf16 helpers (manual RNE; no hip_bf16.h dependency) ----------
static __device__ __forceinline__ unsigned short f2bf(float f) {
    union { float f; unsigned int u; } v; v.f = f;
    unsigned int u = v.u;
    u += 0x7fffu + ((u >> 16) & 1u);
    return (unsigned short)(u >> 16);
}
// pack two f32 -> bf16x2 dword, round-half-up via +0x8000 then byte-perm.
static __device__ __forceinline__ unsigned int packbf2(float lo, float hi) {
    union { float f; unsigned int u; } a, b;
    a.f = lo; b.f = hi;
    return __builtin_amdgcn_perm(b.u + 0x8000u, a.u + 0x8000u, 0x07060302u);
}

// =====================================================================
// Pre-pass A: cast X fp32 -> bf16
// =====================================================================
__global__ __launch_bounds__(256) void cast_x_kernel(
    const float* __restrict__ X, unsigned short* __restrict__ Xb)
{
    const size_t i = ((size_t)blockIdx.x * 256 + threadIdx.x) * 8;
    const float4 a = *(const float4*)(X + i);
    const float4 b = *(const float4*)(X + i + 4);
    u16x8 o;
    o[0] = f2bf(a.x); o[1] = f2bf(a.y); o[2] = f2bf(a.z); o[3] = f2bf(a.w);
    o[4] = f2bf(b.x); o[5] = f2bf(b.y); o[6] = f2bf(b.z); o[7] = f2bf(b.w);
    *(u16x8*)(Xb + i) = o;
}

// =====================================================================
// Pre-pass B: transpose-cast W [K][N] fp32 -> Wt [N][K] bf16
// =====================================================================
__global__ __launch_bounds__(256) void tcast_kernel(
    const float* __restrict__ src, unsigned short* __restrict__ dst,
    int K, int N)
{
    __shared__ float ts[32][33];
    const int t = threadIdx.x;
    const int n0 = blockIdx.x * 32, k0 = blockIdx.y * 32;
    const int r = t >> 5, c = t & 31;
    #pragma unroll
    for (int p = 0; p < 4; ++p)
        ts[r + p * 8][c] = src[(size_t)(k0 + r + p * 8) * N + n0 + c];
    __syncthreads();
    #pragma unroll
    for (int p = 0; p < 4; ++p)
        dst[(size_t)(n0 + r + p * 8) * K + k0 + c] = f2bf(ts[c][r + p * 8]);
}

// =====================================================================
// Kernel 1: QKV projection via bf16 MFMA + fused RoPE + head-split.
// =====================================================================
__global__ __launch_bounds__(256) void proj_qkv_mfma(
    const unsigned short* __restrict__ Xb, const unsigned short* __restrict__ Wt,
    unsigned short* __restrict__ qb, unsigned short* __restrict__ kb,
    unsigned short* __restrict__ vb)
{
    __shared__ __align__(16) unsigned short As[128 * 32];
    __shared__ __align__(16) unsigned short Bs[128 * 32];

    const int t     = threadIdx.x;
    const int w     = t >> 6, lane = t & 63;
    const int lane4 = lane & 15, quad = lane >> 4, quad8 = quad * 8;
    const int wm    = w >> 1, wn = w & 1;
    const int m0    = blockIdx.y * 128, n0 = blockIdx.x * 128;

    const int srow = t >> 2, scol = (t & 3) * 8;
    const unsigned short* gA = Xb + (size_t)(m0 + srow) * DD + scol;
    const unsigned short* gB = Wt + (size_t)(n0 + srow) * DD + scol;
    unsigned short* lA = As + t * 8;
    unsigned short* lB = Bs + t * 8;

    f32x4 acc[4][4] = {};

    for (int k0 = 0; k0 < DD; k0 += 32) {
        __syncthreads();
        ASYNC16(gA + k0,            lA);
        ASYNC16(gA + 64 * DD + k0,  lA + 2048);
        ASYNC16(gB + k0,            lB);
        ASYNC16(gB + 64 * DD + k0,  lB + 2048);
        __syncthreads();

        bf16x8 a[4], b[4];
        #pragma unroll
        for (int i = 0; i < 4; ++i)
            a[i] = *(const bf16x8*)&As[(wm * 64 + i * 16 + lane4) * 32 + quad8];
        #pragma unroll
        for (int j = 0; j < 4; ++j)
            b[j] = *(const bf16x8*)&Bs[(wn * 64 + j * 16 + lane4) * 32 + quad8];
        #pragma unroll
        for (int i = 0; i < 4; ++i)
            #pragma unroll
            for (int j = 0; j < 4; ++j)
                acc[i][j] = MFMA16(a[i], b[j], acc[i][j]);
    }

    // ---- epilogue ----
    const int sec = n0 >> 10;                  // 0=q 1=k 2=v (uniform/block)

    if (sec == 2) {
        // V: transposed global layout, 4 consecutive n per lane -> uint2
        #pragma unroll
        for (int j = 0; j < 4; ++j) {
            const int csec = (n0 & 1023) + wn * 64 + j * 16;
            const int h    = csec >> 6;
            const int dh   = (csec & 63) + lane4;
            #pragma unroll
            for (int i = 0; i < 4; ++i) {
                const int rg0 = m0 + wm * 64 + i * 16 + quad * 4;
                const int b   = rg0 >> 11;
                const int n   = rg0 & 2047;
                uint2 pk;
                pk.x = packbf2(acc[i][j][0], acc[i][j][1]);
                pk.y = packbf2(acc[i][j][2], acc[i][j][3]);
                *(uint2*)(vb + (((size_t)b * HH + h) * DHD + dh) * NN + n) = pk;
            }
        }
    } else {
        unsigned short* dst = (sec == 0) ? qb : kb;
        const float qscale = (sec == 0) ? SCALE_LOG2E : 1.0f;
        #pragma unroll
        for (int j = 0; j < 4; ++j) {
            const int csec = (n0 & 1023) + wn * 64 + j * 16;
            const int h    = csec >> 6;
            const int dhb  = csec & 63;
            const int dh   = dhb + lane4;
            const bool rope = (dhb < 32);          // wave-uniform
            const float invf = fexp2(-(float)(dh >> 1) * LOG2_10K_D16);
            #pragma unroll
            for (int i = 0; i < 4; ++i) {
                #pragma unroll
                for (int r = 0; r < 4; ++r) {
                    const int rg = m0 + wm * 64 + i * 16 + quad * 4 + r;
                    const int b  = rg >> 11;
                    const int n  = rg & 2047;
                    float x = acc[i][j][r] * qscale;
                    if (rope) {
                        const float ang = (float)n * invf;
                        float s_, c_;
                        __sincosf(ang, &s_, &c_);
                        const float p = __shfl_xor(x, 1);
                        x = (lane4 & 1) ? fmaf(p, s_, x * c_)
                                        : fmaf(p, -s_, x * c_);
                    }
                    dst[(((size_t)b * HH + h) * NN + n) * DHD + dh] = f2bf(x);
                }
            }
        }
    }
}

// =====================================================================
// Kernel 2: flash attention, KEY-SPLIT waves + 2-TILE SOFTWARE PIPELINE
// (R9). R4/R5/R8 localization: limiter is the within-wave serial chain
// QK -> exp -> pack -> PV (more occupancy made it worse, R8).
// Pipeline (T15-style): hold P(kt) in regs (pb); per iteration:
//   1. issue global loads for tile kt+2 (regs)
//   2. QK MFMAs for tile kt+1 -> scn        (MFMA pipe)
//   3. PV MFMAs + l-MFMA for tile kt (pb)   (MFMA pipe, indep of 2)
//   4. exp/pack scn -> pb (P(kt+1))         (VALU, overlaps 2/3 next iter)
//   5. write staged tile kt+2 into buffer (kt+2)&1 == kt&1, whose last
//      reader (PV(kt), step 3) precedes it in program order.
// Wave-private staging (R5/R8-proven: addresses disjoint per wave) +
// double buffers -> ZERO barriers; per-wave in-order DS gives RAW/WAR.
// XCD pinning kept: id%8 == bh%8 -> K/V L2-resident.
// =====================================================================
__global__ __launch_bounds__(256, 2) void attn_kernel(
    const unsigned short* __restrict__ qb, const unsigned short* __restrict__ kb,
    const unsigned short* __restrict__ vtb, unsigned short* __restrict__ aob)
{
    __shared__ __align__(16) unsigned char smem[65536];
    unsigned short (*ks)[128][64] = (unsigned short (*)[128][64])smem;           // 2x16KB
    unsigned short (*vs)[64][128] = (unsigned short (*)[64][128])(smem + 32768); // 2x16KB

    const int t     = threadIdx.x;
    const int kq    = t >> 6;          // wave's key-quarter
    const int lane  = t & 63;
    const int lane4 = lane & 15;
    const int quad  = lane >> 4;
    const int quad8 = quad * 8;
    const int l7    = lane4 & 7;

    const int bid = blockIdx.x;
    const int bh  = bid & 63;          // id%8 = bh%8 -> per-XCD head groups
    const int q0  = (bid >> 6) * 64;
    const size_t hb = (size_t)bh * NN * DHD;

    // Q B-fragments for ALL 64 queries (held in registers whole kernel)
    bf16x8 qf[4][2];
    #pragma unroll
    for (int qt = 0; qt < 4; ++qt) {
        const unsigned short* qrow = qb + hb + (size_t)(q0 + qt * 16 + lane4) * DHD;
        qf[qt][0] = *(const bf16x8*)(qrow + quad8);
        qf[qt][1] = *(const bf16x8*)(qrow + 32 + quad8);
    }

    // ones A-fragment for the l-accumulating MFMA
    bf16x8 onesf;
    #pragma unroll
    for (int j = 0; j < 8; ++j) onesf[j] = (short)0x3F80;

    // ---- wave-private staging maps (each wave stages ONLY its keys) ----
    // K: 4 chunks, rows (within tile) = kq*16 + (lane>>3) + {0, 8, 64, 72},
    //    global col (lane&7)*8, LDS slot (lane&7)^(lane>>3) (row&7 == lane>>3)
    const int krow  = kq * 16 + (lane >> 3);
    const int kslot = ((lane & 7) ^ (lane >> 3)) * 8;
    const unsigned short* kg = kb + hb + (size_t)krow * DHD + (lane & 7) * 8;

    // V: 4 chunks s=0..3, rows = (lane>>2) + 16*s, key-group
    //    vm = 2kq + (lane&1) + ((lane>>1)&1)*8  (wave's 4 of 16 groups);
    //    8 keys -> logical slots (vm&7)*2 (lo4) and (vm&7)*2+1 (hi4),
    //    half-offset (vm>>3)*4, physical slot XOR row&7 (== vrow0&7).
    const int vrow0 = lane >> 2;
    const int vm    = 2 * kq + (lane & 1) + ((lane >> 1) & 1) * 8;
    const int vr7   = vrow0 & 7;
    const int halfo = (vm >> 3) * 4;
    const int colA  = ((((vm & 7) * 2)     ^ vr7) * 8) + halfo;
    const int colB  = ((((vm & 7) * 2 + 1) ^ vr7) * 8) + halfo;
    const unsigned short* vg = vtb + hb + (size_t)vrow0 * NN + vm * 8;

    f32x4 o[4][4], lacc[4];
    #pragma unroll
    for (int d = 0; d < 4; ++d)
        #pragma unroll
        for (int qt = 0; qt < 4; ++qt) o[d][qt] = (f32x4){0.f, 0.f, 0.f, 0.f};
    #pragma unroll
    for (int qt = 0; qt < 4; ++qt) lacc[qt] = (f32x4){0.f, 0.f, 0.f, 0.f};

    // ---- prologue: stage tiles 0 and 1 (wave-private, no barrier) ----
    {
        const bf16x8 a0 = *(const bf16x8*)(kg);
        const bf16x8 a1 = *(const bf16x8*)(kg + 8 * DHD);
        const bf16x8 a2 = *(const bf16x8*)(kg + 64 * DHD);
        const bf16x8 a3 = *(const bf16x8*)(kg + 72 * DHD);
        const bf16x8 b0 = *(const bf16x8*)(vg);
        const bf16x8 b1 = *(const bf16x8*)(vg + (size_t)16 * NN);
        const bf16x8 b2 = *(const bf16x8*)(vg + (size_t)32 * NN);
        const bf16x8 b3 = *(const bf16x8*)(vg + (size_t)48 * NN);
        const unsigned short* kg1 = kg + (size_t)128 * DHD;
        const unsigned short* vg1 = vg + 128;
        const bf16x8 c0 = *(const bf16x8*)(kg1);
        const bf16x8 c1 = *(const bf16x8*)(kg1 + 8 * DHD);
        const bf16x8 c2 = *(const bf16x8*)(kg1 + 64 * DHD);
        const bf16x8 c3 = *(const bf16x8*)(kg1 + 72 * DHD);
        const bf16x8 d0 = *(const bf16x8*)(vg1);
        const bf16x8 d1 = *(const bf16x8*)(vg1 + (size_t)16 * NN);
        const bf16x8 d2 = *(const bf16x8*)(vg1 + (size_t)32 * NN);
        const bf16x8 d3 = *(const bf16x8*)(vg1 + (size_t)48 * NN);

        *(bf16x8*)&ks[0][krow][kslot]      = a0;
        *(bf16x8*)&ks[0][krow + 8][kslot]  = a1;
        *(bf16x8*)&ks[0][krow + 64][kslot] = a2;
        *(bf16x8*)&ks[0][krow + 72][kslot] = a3;
        #pragma unroll
        for (int s = 0; s < 4; ++s) {
            const bf16x8 vv = (s == 0) ? b0 : (s == 1) ? b1 : (s == 2) ? b2 : b3;
            bf16x4 lo = __builtin_shufflevector(vv, vv, 0, 1, 2, 3);
            bf16x4 hi = __builtin_shufflevector(vv, vv, 4, 5, 6, 7);
            *(bf16x4*)&vs[0][vrow0 + 16 * s][colA] = lo;
            *(bf16x4*)&vs[0][vrow0 + 16 * s][colB] = hi;
        }
        *(bf16x8*)&ks[1][krow][kslot]      = c0;
        *(bf16x8*)&ks[1][krow + 8][kslot]  = c1;
        *(bf16x8*)&ks[1][krow + 64][kslot] = c2;
        *(bf16x8*)&ks[1][krow + 72][kslot] = c3;
        #pragma unroll
        for (int s = 0; s < 4; ++s) {
            const bf16x8 vv = (s == 0) ? d0 : (s == 1) ? d1 : (s == 2) ? d2 : d3;
            bf16x4 lo = __builtin_shufflevector(vv, vv, 0, 1, 2, 3);
            bf16x4 hi = __builtin_shufflevector(vv, vv, 4, 5, 6, 7);
            *(bf16x4*)&vs[1][vrow0 + 16 * s][colA] = lo;
            *(bf16x4*)&vs[1][vrow0 + 16 * s][colB] = hi;
        }
    }

    // ---- prologue compute: P(0) -> pb ----
    bf16x8 pb[4];
    {
        bf16x8 ak[2][2];
        #pragma unroll
        for (int sub = 0; sub < 2; ++sub) {
            const int row = sub * 64 + kq * 16 + lane4;
            ak[sub][0] = *(const bf16x8*)&ks[0][row][(quad ^ l7) * 8];
            ak[sub][1] = *(const bf16x8*)&ks[0][row][((quad + 4) ^ l7) * 8];
        }
        #pragma unroll
        for (int qt = 0; qt < 4; ++qt) {
            f32x4 z0 = (f32x4){0.f, 0.f, 0.f, 0.f};
            f32x4 z1 = (f32x4){0.f, 0.f, 0.f, 0.f};
            z0 = MFMA16(ak[0][0], qf[qt][0], z0);
            z0 = MFMA16(ak[0][1], qf[qt][1], z0);
            z1 = MFMA16(ak[1][0], qf[qt][0], z1);
            z1 = MFMA16(ak[1][1], qf[qt][1], z1);
            union { unsigned int u[4]; bf16x8 v; } pk;
            pk.u[0] = packbf2(fexp2(z0[0]), fexp2(z0[1]));
            pk.u[1] = packbf2(fexp2(z0[2]), fexp2(z0[3]));
            pk.u[2] = packbf2(fexp2(z1[0]), fexp2(z1[1]));
            pk.u[3] = packbf2(fexp2(z1[2]), fexp2(z1[3]));
            pb[qt] = pk.v;
        }
    }

    for (int kt = 0; kt < NN / 128; ++kt) {
        const int cur = kt & 1;
        const bool more1 = (kt + 1 < NN / 128);
        const bool more2 = (kt + 2 < NN / 128);

        // ---- 1. issue tile kt+2 global loads (land during compute) ----
        bf16x8 nk0, nk1, nk2, nk3, nv0, nv1, nv2, nv3;
        if (more2) {
            const unsigned short* kgn = kg + (size_t)(kt + 2) * 128 * DHD;
            const unsigned short* vgn = vg + (kt + 2) * 128;
            nk0 = *(const bf16x8*)(kgn);
            nk1 = *(const bf16x8*)(kgn + 8 * DHD);
            nk2 = *(const bf16x8*)(kgn + 64 * DHD);
            nk3 = *(const bf16x8*)(kgn + 72 * DHD);
            nv0 = *(const bf16x8*)(vgn);
            nv1 = *(const bf16x8*)(vgn + (size_t)16 * NN);
            nv2 = *(const bf16x8*)(vgn + (size_t)32 * NN);
            nv3 = *(const bf16x8*)(vgn + (size_t)48 * NN);
        }

        // ---- 2. QK MFMAs for tile kt+1 -> scn ----
        f32x4 scn[4][2];
        if (more1) {
            bf16x8 ak[2][2];
            #pragma unroll
            for (int sub = 0; sub < 2; ++sub) {
                const int row = sub * 64 + kq * 16 + lane4;
                ak[sub][0] = *(const bf16x8*)&ks[cur ^ 1][row][(quad ^ l7) * 8];
                ak[sub][1] = *(const bf16x8*)&ks[cur ^ 1][row][((quad + 4) ^ l7) * 8];
            }
            #pragma unroll
            for (int qt = 0; qt < 4; ++qt) {
                f32x4 z0 = (f32x4){0.f, 0.f, 0.f, 0.f};
                f32x4 z1 = (f32x4){0.f, 0.f, 0.f, 0.f};
                z0 = MFMA16(ak[0][0], qf[qt][0], z0);
                z0 = MFMA16(ak[0][1], qf[qt][1], z0);
                z1 = MFMA16(ak[1][0], qf[qt][0], z1);
                z1 = MFMA16(ak[1][1], qf[qt][1], z1);
                scn[qt][0] = z0;
                scn[qt][1] = z1;
            }
        }

        // ---- 3. PV + l-MFMA for tile kt using pb (indep of step 2) ----
        #pragma unroll
        for (int d = 0; d < 4; ++d) {
            const bf16x8 av = *(const bf16x8*)&vs[cur][d * 16 + lane4][((kq * 4 + quad) ^ l7) * 8];
            #pragma unroll
            for (int qt = 0; qt < 4; ++qt)
                o[d][qt] = MFMA16(av, pb[qt], o[d][qt]);
        }
        #pragma unroll
        for (int qt = 0; qt < 4; ++qt)
            lacc[qt] = MFMA16(onesf, pb[qt], lacc[qt]);

        // ---- 4. exp/pack scn -> pb (P of tile kt+1) ----
        if (more1) {
            #pragma unroll
            for (int qt = 0; qt < 4; ++qt) {
                union { unsigned int u[4]; bf16x8 v; } pk;
                pk.u[0] = packbf2(fexp2(scn[qt][0][0]), fexp2(scn[qt][0][1]));
                pk.u[1] = packbf2(fexp2(scn[qt][0][2]), fexp2(scn[qt][0][3]));
                pk.u[2] = packbf2(fexp2(scn[qt][1][0]), fexp2(scn[qt][1][1]));
                pk.u[3] = packbf2(fexp2(scn[qt][1][2]), fexp2(scn[qt][1][3]));
                pb[qt] = pk.v;
            }
        }

        // ---- 5. write tile kt+2 into buf cur (freed by PV(kt) above) ----
        if (more2) {
            *(bf16x8*)&ks[cur][krow][kslot]      = nk0;
            *(bf16x8*)&ks[cur][krow + 8][kslot]  = nk1;
            *(bf16x8*)&ks[cur][krow + 64][kslot] = nk2;
            *(bf16x8*)&ks[cur][krow + 72][kslot] = nk3;
            #pragma unroll
            for (int s = 0; s < 4; ++s) {
                const bf16x8 vv = (s == 0) ? nv0 : (s == 1) ? nv1 : (s == 2) ? nv2 : nv3;
                bf16x4 lo = __builtin_shufflevector(vv, vv, 0, 1, 2, 3);
                bf16x4 hi = __builtin_shufflevector(vv, vv, 4, 5, 6, 7);
                *(bf16x4*)&vs[cur][vrow0 + 16 * s][colA] = lo;
                *(bf16x4*)&vs[cur][vrow0 + 16 * s][colB] = hi;
            }
        }
        // NO barrier: staging is wave-private (disjoint addresses)
    }

    // ---- epilogue: cross-wave O reduction via LDS overlay ----
    __syncthreads();   // all waves done with their private ks/vs regions
    float* pbuf = (float*)smem;   // [w][dh 64][q 64] f32 = 64 KB
    #pragma unroll
    for (int d = 0; d < 4; ++d)
        #pragma unroll
        for (int qt = 0; qt < 4; ++qt)
            #pragma unroll
            for (int r = 0; r < 4; ++r)
                pbuf[(kq * 64 + d * 16 + quad * 4 + r) * 64 + qt * 16 + lane4] = o[d][qt][r];
    __syncthreads();

    // wave kq finalizes q-tile kq (all dh)
    f32x4 of[4];
    #pragma unroll
    for (int d = 0; d < 4; ++d)
        #pragma unroll
        for (int r = 0; r < 4; ++r) {
            const int dh = d * 16 + quad * 4 + r;
            const int qc = kq * 16 + lane4;
            of[d][r] = pbuf[dh * 64 + qc] + pbuf[(64 + dh) * 64 + qc]
                     + pbuf[(128 + dh) * 64 + qc] + pbuf[(192 + dh) * 64 + qc];
        }
    __syncthreads();

    // l exchange (reuse first 1 KB of the overlay after O is consumed)
    if (quad == 0) {
        #pragma unroll
        for (int qt = 0; qt < 4; ++qt)
            pbuf[(kq * 4 + qt) * 16 + lane4] = lacc[qt][0];
    }
    __syncthreads();
    const float lt = pbuf[(0 * 4 + kq) * 16 + lane4] + pbuf[(1 * 4 + kq) * 16 + lane4]
                   + pbuf[(2 * 4 + kq) * 16 + lane4] + pbuf[(3 * 4 + kq) * 16 + lane4];
    const float linv = 1.0f / lt;

    const int b = bh >> 4, h = bh & 15;
    const int n = q0 + kq * 16 + lane4;
    unsigned short* obase = aob + ((size_t)b * NN + n) * INNER + h * DHD;
    #pragma unroll
    for (int d = 0; d < 4; ++d) {
        uint2 pk;
        pk.x = packbf2(of[d][0] * linv, of[d][1] * linv);
        pk.y = packbf2(of[d][2] * linv, of[d][3] * linv);
        *(uint2*)(obase + d * 16 + quad * 4) = pk;
    }
}

// =====================================================================
// Kernel 3: output projection via bf16 MFMA.
// =====================================================================
__global__ __launch_bounds__(256) void out_proj_mfma(
    const unsigned short* __restrict__ Ab, const unsigned short* __restrict__ Wt,
    const float* __restrict__ bias, float* __restrict__ C)
{
    __shared__ __align__(16) unsigned short As[128 * 32];
    __shared__ __align__(16) unsigned short Bs[128 * 32];

    const int t     = threadIdx.x;
    const int w     = t >> 6, lane = t & 63;
    const int lane4 = lane & 15, quad = lane >> 4, quad8 = quad * 8;
    const int wm    = w >> 1, wn = w & 1;
    const int m0    = blockIdx.y * 128, n0 = blockIdx.x * 128;

    const int srow = t >> 2, scol = (t & 3) * 8;
    const unsigned short* gA = Ab + (size_t)(m0 + srow) * INNER + scol;
    const unsigned short* gB = Wt + (size_t)(n0 + srow) * INNER + scol;
    unsigned short* lA = As + t * 8;
    unsigned short* lB = Bs + t * 8;

    f32x4 acc[4][4] = {};

    for (int k0 = 0; k0 < INNER; k0 += 32) {
        __syncthreads();
        ASYNC16(gA + k0,               lA);
        ASYNC16(gA + 64 * INNER + k0,  lA + 2048);
        ASYNC16(gB + k0,               lB);
        ASYNC16(gB + 64 * INNER + k0,  lB + 2048);
        __syncthreads();

        bf16x8 a[4], b[4];
        #pragma unroll
        for (int i = 0; i < 4; ++i)
            a[i] = *(const bf16x8*)&As[(wm * 64 + i * 16 + lane4) * 32 + quad8];
        #pragma unroll
        for (int j = 0; j < 4; ++j)
            b[j] = *(const bf16x8*)&Bs[(wn * 64 + j * 16 + lane4) * 32 + quad8];
        #pragma unroll
        for (int i = 0; i < 4; ++i)
            #pragma unroll
            for (int j = 0; j < 4; ++j)
                acc[i][j] = MFMA16(a[i], b[j], acc[i][j]);
    }

    #pragma unroll
    for (int j = 0; j < 4; ++j) {
        const int col = n0 + wn * 64 + j * 16 + lane4;
        const float bv = bias[col];
        #pragma unroll
        for (int i = 0; i < 4; ++i)
            #pragma unroll
            for (int r = 0; r < 4; ++r) {
                const int rg = m0 + wm * 64 + i * 16 + quad * 4 + r;
                C[(size_t)rg * DD + col] = acc[i][j][r] + bv;
            }
    }
}

// =====================================================================
extern "C" void kernel_launch(void* const* d_in, const int* in_sizes, int n_in,
                              void* d_out, int out_size, void* d_ws, size_t ws_size,
                              hipStream_t stream)
{
    const float* X    = (const float*)d_in[0];   // (4,2048,1024)
    const float* Wq   = (const float*)d_in[1];   // (1024,1024)
    const float* Wkv  = (const float*)d_in[2];   // (1024,2048)
    const float* Wout = (const float*)d_in[3];   // (1024,1024)
    const float* bout = (const float*)d_in[4];   // (1024,)
    float* out = (float*)d_out;

    // ws (bf16 elems): qb|kb|vtb|xb(=aob after proj)|WtAll|WoT = 75.5 MB
    const size_t E = (size_t)BB * HH * NN * DHD;   // 8388608
    unsigned short* qb  = (unsigned short*)d_ws;
    unsigned short* kb  = qb + E;
    unsigned short* vtb = kb + E;                // V^T [b][h][dh][n]
    unsigned short* xb  = vtb + E;               // X bf16; later reused as ao
    unsigned short* wt  = xb + E;                // [3072][1024] = WqT ; WkvT
    unsigned short* wo  = wt + (size_t)3072 * 1024;  // [1024][1024]

    cast_x_kernel<<<4096, 256, 0, stream>>>(X, xb);
    tcast_kernel<<<dim3(32, 32), 256, 0, stream>>>(Wq,   wt,               1024, 1024);
    tcast_kernel<<<dim3(64, 32), 256, 0, stream>>>(Wkv,  wt + 1024 * 1024, 1024, 2048);
    tcast_kernel<<<dim3(32, 32), 256, 0, stream>>>(Wout, wo,               1024, 1024);

    proj_qkv_mfma<<<dim3(3072 / 128, 8192 / 128), 256, 0, stream>>>(
        xb, wt, qb, kb, vtb);

    attn_kernel<<<dim3(NN / 64 * BB * HH), 256, 0, stream>>>(qb, kb, vtb, xb);

    out_proj_mfma<<<dim3(1024 / 128, 8192 / 128), 256, 0, stream>>>(
        xb, wo, bout, out);
}